// Round 7
// baseline (707.786 us; speedup 1.0000x reference)
//
#include <hip/hip_runtime.h>
#include <cstddef>

#define N_NODES  100000
#define N_EDGES  640000
#define WIDTH    128
#define LAYERS   3
#define N_GRAPHS 64

#define SCAN_CHUNK 1024
#define NBLK ((N_NODES + SCAN_CHUNK - 1) / SCAN_CHUNK)  // 98

// ---------------- setup kernels ----------------

__global__ void k_init(int* __restrict__ counts, int* __restrict__ counts2) {
  int i = blockIdx.x * blockDim.x + threadIdx.x;
  if (i < N_NODES) { counts[i] = 0; counts2[i] = 0; }
}

// count in-degree (col) and out-degree (row)
__global__ void k_count(const int* __restrict__ row, const int* __restrict__ col,
                        int* __restrict__ counts, int* __restrict__ counts2) {
  int e = blockIdx.x * blockDim.x + threadIdx.x;
  if (e < N_EDGES) {
    atomicAdd(&counts[col[e]], 1);
    atomicAdd(&counts2[row[e]], 1);
  }
}

__global__ void k_scan1(const int* __restrict__ counts, int* __restrict__ bsum) {
  __shared__ int sd[256];
  int t = threadIdx.x;
  int base = blockIdx.x * SCAN_CHUNK;
  int s = 0;
  for (int j = t; j < SCAN_CHUNK; j += 256) {
    int idx = base + j;
    if (idx < N_NODES) s += counts[idx];
  }
  sd[t] = s; __syncthreads();
  for (int off = 128; off > 0; off >>= 1) {
    if (t < off) sd[t] += sd[t + off];
    __syncthreads();
  }
  if (t == 0) bsum[blockIdx.x] = sd[0];
}

__global__ void k_scan2(int* __restrict__ bsum) {
  if (threadIdx.x == 0 && blockIdx.x == 0) {
    int acc = 0;
    for (int i = 0; i < NBLK; i++) { int v = bsum[i]; bsum[i] = acc; acc += v; }
  }
}

__global__ void k_scan3(const int* __restrict__ counts, const int* __restrict__ bsum,
                        int* __restrict__ offs, int* __restrict__ cursor) {
  __shared__ int sd[256];
  int t = threadIdx.x;
  int base = blockIdx.x * SCAN_CHUNK;
  int idx0 = base + t * 4;
  int v0 = (idx0 + 0 < N_NODES) ? counts[idx0 + 0] : 0;
  int v1 = (idx0 + 1 < N_NODES) ? counts[idx0 + 1] : 0;
  int v2 = (idx0 + 2 < N_NODES) ? counts[idx0 + 2] : 0;
  int v3 = (idx0 + 3 < N_NODES) ? counts[idx0 + 3] : 0;
  int s = v0 + v1 + v2 + v3;
  sd[t] = s; __syncthreads();
  for (int off = 1; off < 256; off <<= 1) {
    int val = (t >= off) ? sd[t - off] : 0;
    __syncthreads();
    sd[t] += val;
    __syncthreads();
  }
  int e0 = sd[t] - s + bsum[blockIdx.x];
  if (idx0 + 0 < N_NODES) { offs[idx0 + 0] = e0; cursor[idx0 + 0] = e0; } e0 += v0;
  if (idx0 + 1 < N_NODES) { offs[idx0 + 1] = e0; cursor[idx0 + 1] = e0; } e0 += v1;
  if (idx0 + 2 < N_NODES) { offs[idx0 + 2] = e0; cursor[idx0 + 2] = e0; } e0 += v2;
  if (idx0 + 3 < N_NODES) { offs[idx0 + 3] = e0; cursor[idx0 + 3] = e0; } e0 += v3;
  if (blockIdx.x == NBLK - 1 && t == 255) offs[N_NODES] = e0;
}

// col-CSR fill with raw edge weight (for degree)
__global__ void k_fill(const int* __restrict__ row, const int* __restrict__ col,
                       const float* __restrict__ ew, int* __restrict__ cursor,
                       int* __restrict__ csr_r, float* __restrict__ csr_w) {
  int e = blockIdx.x * blockDim.x + threadIdx.x;
  if (e < N_EDGES) {
    int c = col[e];
    int slot = atomicAdd(&cursor[c], 1);
    csr_r[slot] = row[e];
    csr_w[slot] = ew[e];
  }
}

// deg[v] = 2 + sum incoming w; dinv = rsqrt
__global__ void k_dinv(const int* __restrict__ offs, const float* __restrict__ csr_w,
                       float* __restrict__ dinv) {
  int v = blockIdx.x * blockDim.x + threadIdx.x;
  if (v < N_NODES) {
    int s0 = offs[v], s1 = offs[v + 1];
    float d = 2.0f;
    for (int s = s0; s < s1; s++) d += csr_w[s];
    dinv[v] = (d > 0.0f) ? 1.0f / sqrtf(d) : 0.0f;
  }
}

// csr_n[slot] <- dinv[row]*w*dinv[col]  (col-CSR)
__global__ void k_norm(const int* __restrict__ offs, const int* __restrict__ csr_r,
                       const float* __restrict__ dinv, float* __restrict__ csr_w) {
  int v = blockIdx.x * blockDim.x + threadIdx.x;
  if (v < N_NODES) {
    float dv = dinv[v];
    int s0 = offs[v], s1 = offs[v + 1];
    for (int s = s0; s < s1; s++) csr_w[s] = dinv[csr_r[s]] * csr_w[s] * dv;
  }
}

// row-CSR fill, directly normalized (dinv ready)
__global__ void k_fill2(const int* __restrict__ row, const int* __restrict__ col,
                        const float* __restrict__ ew, const float* __restrict__ dinv,
                        int* __restrict__ cursor2,
                        int* __restrict__ csr2_c, float* __restrict__ csr2_n) {
  int e = blockIdx.x * blockDim.x + threadIdx.x;
  if (e < N_EDGES) {
    int r = row[e], c = col[e];
    int slot = atomicAdd(&cursor2[r], 1);
    csr2_c[slot] = c;
    csr2_n[slot] = dinv[r] * ew[e] * dinv[c];
  }
}

__device__ __forceinline__ int lbound(const int* __restrict__ batch, int key) {
  int lo = 0, hi = N_NODES;
  while (lo < hi) { int m = (lo + hi) >> 1; if (batch[m] < key) lo = m + 1; else hi = m; }
  return lo;
}

// per-graph counts + 1/max(cnt,1)
__global__ void k_cntg(const int* __restrict__ batch, int* __restrict__ cntg,
                       float* __restrict__ invc) {
  int g = threadIdx.x;
  if (g < N_GRAPHS) {
    int lb = lbound(batch, g), ub = lbound(batch, g + 1);
    int c = ub - lb;
    cntg[g] = c;
    invc[g] = 1.0f / (float)max(c, 1);
  }
}

// p[v][g] = (batch[v]==g) * invc[g]   (P^T, N x 64 f32)
__global__ void k_pinit(const int* __restrict__ batch, const float* __restrict__ invc,
                        float* __restrict__ p) {
  const int total = N_NODES * 16;   // float4 count
  for (int i = blockIdx.x * blockDim.x + threadIdx.x; i < total;
       i += gridDim.x * blockDim.x) {
    int v = i >> 4, q = i & 15;
    int b = batch[v];
    float f[4];
#pragma unroll
    for (int k = 0; k < 4; k++) f[k] = (q * 4 + k == b) ? invc[b] : 0.0f;
    *(float4*)(p + (size_t)v * 64 + q * 4) = make_float4(f[0], f[1], f[2], f[3]);
  }
}

// s[v] = (A*1)[v] = 2*dinv^2 + sum of incoming norms (col-CSR)
__global__ void k_s(const int* __restrict__ offs, const float* __restrict__ csr_n,
                    const float* __restrict__ dinv, float* __restrict__ s_) {
  int v = blockIdx.x * blockDim.x + threadIdx.x;
  if (v < N_NODES) {
    float dv = dinv[v];
    float a = 2.0f * dv * dv;
    int s0 = offs[v], s1 = offs[v + 1];
    for (int s = s0; s < s1; s++) a += csr_n[s];
    s_[v] = a;
  }
}

// as[v] = (A*s)[v] = 2*dinv^2*s[v] + sum norm*s[row]
__global__ void k_as(const int* __restrict__ offs, const int* __restrict__ csr_r,
                     const float* __restrict__ csr_n, const float* __restrict__ dinv,
                     const float* __restrict__ s_, float* __restrict__ as_) {
  int v = blockIdx.x * blockDim.x + threadIdx.x;
  if (v < N_NODES) {
    float dv = dinv[v];
    float a = 2.0f * dv * dv * s_[v];
    int s0 = offs[v], s1 = offs[v + 1];
    for (int s = s0; s < s1; s++) a += csr_n[s] * s_[csr_r[s]];
    as_[v] = a;
  }
}

// ps[g] = mean of s over graph g; pas[g] = mean of as
__global__ __launch_bounds__(256) void k_psum(
    const int* __restrict__ batch, const float* __restrict__ invc,
    const float* __restrict__ s_, const float* __restrict__ as_,
    float* __restrict__ ps, float* __restrict__ pas) {
  __shared__ float sd[256];
  int g = blockIdx.x, t = threadIdx.x;
  int lb = lbound(batch, g), ub = lbound(batch, g + 1);
  float a1 = 0.f, a2 = 0.f;
  for (int i = lb + t; i < ub; i += 256) { a1 += s_[i]; a2 += as_[i]; }
  sd[t] = a1; __syncthreads();
  for (int off = 128; off > 0; off >>= 1) { if (t < off) sd[t] += sd[t + off]; __syncthreads(); }
  float tot1 = sd[0]; __syncthreads();
  sd[t] = a2; __syncthreads();
  for (int off = 128; off > 0; off >>= 1) { if (t < off) sd[t] += sd[t + off]; __syncthreads(); }
  if (t == 0) { ps[g] = tot1 * invc[g]; pas[g] = sd[0] * invc[g]; }
}

// ---------------- y-chain: yOut = A^T yIn  (row-CSR gather, 64-wide f32) ----------------
// wave per node: 16 lanes x float4 cover the 64-float row; 4 edge-groups.
#define AGG_NPB 4
__global__ __launch_bounds__(256) void k_yagg(
    const float* __restrict__ yin, const int* __restrict__ offs2,
    const int* __restrict__ csr2_c, const float* __restrict__ csr2_n,
    const float* __restrict__ dinv, float* __restrict__ yout) {
  int wave = threadIdx.x >> 6;
  int lane = threadIdx.x & 63;
  int v = blockIdx.x * AGG_NPB + wave;
  if (v >= N_NODES) return;
  int grp = lane >> 4;    // 0..3 edge group
  int q = lane & 15;      // float4 slot (16 x 4 = 64 floats)

  float4 a0 = {0,0,0,0}, a1 = {0,0,0,0}, a2 = {0,0,0,0}, a3 = {0,0,0,0};
  int s0 = offs2[v], s1 = offs2[v + 1];

  for (int c0 = s0; c0 < s1; c0 += 64) {
    int cc = min(64, s1 - c0);
    int   si = (lane < cc) ? csr2_c[c0 + lane] : 0;
    float swv = (lane < cc) ? csr2_n[c0 + lane] : 0.f;
    for (int base = 0; base < cc; base += 16) {
      int e0 = base + 0 + grp;
      int e1 = base + 4 + grp;
      int e2 = base + 8 + grp;
      int e3 = base + 12 + grp;
      float w0 = __shfl(swv, e0); int i0 = __shfl(si, e0);
      float w1 = __shfl(swv, e1); int i1 = __shfl(si, e1);
      float w2 = __shfl(swv, e2); int i2 = __shfl(si, e2);
      float w3 = __shfl(swv, e3); int i3 = __shfl(si, e3);
      float4 v0 = *(const float4*)(yin + (size_t)i0 * 64 + q * 4);
      float4 v1 = *(const float4*)(yin + (size_t)i1 * 64 + q * 4);
      float4 v2 = *(const float4*)(yin + (size_t)i2 * 64 + q * 4);
      float4 v3 = *(const float4*)(yin + (size_t)i3 * 64 + q * 4);
      a0.x += w0 * v0.x; a0.y += w0 * v0.y; a0.z += w0 * v0.z; a0.w += w0 * v0.w;
      a1.x += w1 * v1.x; a1.y += w1 * v1.y; a1.z += w1 * v1.z; a1.w += w1 * v1.w;
      a2.x += w2 * v2.x; a2.y += w2 * v2.y; a2.z += w2 * v2.z; a2.w += w2 * v2.w;
      a3.x += w3 * v3.x; a3.y += w3 * v3.y; a3.z += w3 * v3.z; a3.w += w3 * v3.w;
    }
  }

  a0.x += a1.x + a2.x + a3.x;
  a0.y += a1.y + a2.y + a3.y;
  a0.z += a1.z + a2.z + a3.z;
  a0.w += a1.w + a2.w + a3.w;
#pragma unroll
  for (int d = 16; d <= 32; d <<= 1) {
    a0.x += __shfl_xor(a0.x, d);
    a0.y += __shfl_xor(a0.y, d);
    a0.z += __shfl_xor(a0.z, d);
    a0.w += __shfl_xor(a0.w, d);
  }

  if (grp == 0) {
    float dv = dinv[v];
    float sc = 2.0f * dv * dv;
    float4 hv = *(const float4*)(yin + (size_t)v * 64 + q * 4);
    float4 r;
    r.x = a0.x + sc * hv.x;
    r.y = a0.y + sc * hv.y;
    r.z = a0.z + sc * hv.z;
    r.w = a0.w + sc * hv.w;
    *(float4*)(yout + (size_t)v * 64 + q * 4) = r;
  }
}

// ---------------- contraction: part[b] += Y3[v][g] * x0[v][j] ----------------
#define CB_NB 1024
#define CB_CH ((N_NODES + CB_NB - 1) / CB_NB)   // 98
__global__ __launch_bounds__(256) void k_contract(
    const float* __restrict__ x0, const float* __restrict__ y3,
    float* __restrict__ part) {
  int b = blockIdx.x, t = threadIdx.x;
  int g = t >> 2, j4 = t & 3;
  float acc[32];
#pragma unroll
  for (int i = 0; i < 32; i++) acc[i] = 0.f;
  int start = b * CB_CH, end = min(start + CB_CH, N_NODES);
  for (int v = start; v < end; v++) {
    float yv = y3[(size_t)v * 64 + g];
    const float4* xr = (const float4*)(x0 + (size_t)v * WIDTH) + j4 * 8;
#pragma unroll
    for (int k = 0; k < 8; k++) {
      float4 xv = xr[k];
      acc[k * 4 + 0] += yv * xv.x;
      acc[k * 4 + 1] += yv * xv.y;
      acc[k * 4 + 2] += yv * xv.z;
      acc[k * 4 + 3] += yv * xv.w;
    }
  }
  float* dst = part + (size_t)b * (N_GRAPHS * WIDTH) + g * WIDTH + j4 * 32;
#pragma unroll
  for (int k = 0; k < 8; k++)
    *(float4*)(dst + k * 4) = make_float4(acc[k*4+0], acc[k*4+1], acc[k*4+2], acc[k*4+3]);
}

__global__ void k_reduceC(const float* __restrict__ part, float* __restrict__ C) {
  int idx = blockIdx.x * blockDim.x + threadIdx.x;   // 0..8191
  if (idx < N_GRAPHS * WIDTH) {
    float a = 0.f;
    for (int b = 0; b < CB_NB; b++) a += part[(size_t)b * (N_GRAPHS * WIDTH) + idx];
    C[idx] = a;
  }
}

// O = A*B (128x128 f32); block=row, thread=col
__global__ __launch_bounds__(WIDTH) void k_mm128(
    const float* __restrict__ A, const float* __restrict__ B, float* __restrict__ O) {
  __shared__ float Ar[WIDTH];
  int r = blockIdx.x, j = threadIdx.x;
  Ar[j] = A[r * WIDTH + j];
  __syncthreads();
  float a = 0.f;
#pragma unroll 8
  for (int k = 0; k < WIDTH; k++) a += Ar[k] * B[k * WIDTH + j];
  O[r * WIDTH + j] = a;
}

// c0 = b0^T * T1 ; c1 = b1^T * W2
__global__ __launch_bounds__(WIDTH) void k_c01(
    const float* __restrict__ b0, const float* __restrict__ T1,
    const float* __restrict__ b1, const float* __restrict__ W2,
    float* __restrict__ c0, float* __restrict__ c1) {
  __shared__ float s0[WIDTH], s1v[WIDTH];
  int j = threadIdx.x;
  s0[j] = b0[j]; s1v[j] = b1[j];
  __syncthreads();
  float a0 = 0.f, a1 = 0.f;
#pragma unroll 8
  for (int k = 0; k < WIDTH; k++) {
    a0 += s0[k] * T1[k * WIDTH + j];
    a1 += s1v[k] * W2[k * WIDTH + j];
  }
  c0[j] = a0; c1[j] = a1;
}

// out[g][j] = sum_k C[g][k] Wp[k][j] + pas[g]*c0[j] + ps[g]*c1[j] + (cnt>0)*b2[j]
__global__ __launch_bounds__(WIDTH) void k_out(
    const float* __restrict__ C, const float* __restrict__ Wp,
    const float* __restrict__ c0, const float* __restrict__ c1,
    const float* __restrict__ ps, const float* __restrict__ pas,
    const int* __restrict__ cntg, const float* __restrict__ b2,
    float* __restrict__ out) {
  __shared__ float Cr[WIDTH];
  int g = blockIdx.x, j = threadIdx.x;
  Cr[j] = C[g * WIDTH + j];
  __syncthreads();
  float a = pas[g] * c0[j] + ps[g] * c1[j] + ((cntg[g] > 0) ? b2[j] : 0.f);
#pragma unroll 8
  for (int k = 0; k < WIDTH; k++) a += Cr[k] * Wp[k * WIDTH + j];
  out[g * WIDTH + j] = a;
}

// ---------------- launch ----------------

extern "C" void kernel_launch(void* const* d_in, const int* in_sizes, int n_in,
                              void* d_out, int out_size, void* d_ws, size_t ws_size,
                              hipStream_t stream) {
  const float* x   = (const float*)d_in[0];
  const int* row   = (const int*)d_in[1];         // edge_index[0]
  const int* col   = row + N_EDGES;               // edge_index[1]
  const float* ew  = (const float*)d_in[2];
  const int* batch = (const int*)d_in[3];
  const float* Ws  = (const float*)d_in[4];
  const float* bs  = (const float*)d_in[5];
  float* out = (float*)d_out;

  char* w = (char*)d_ws;
  float* dinv    = (float*)(w + 0);
  float* s_      = (float*)(w + 400128);
  float* as_     = (float*)(w + 800256);
  int*   counts  = (int*)(w + 1200384);
  int*   counts2 = (int*)(w + 1600512);
  int*   offs    = (int*)(w + 2000640);
  int*   offs2   = (int*)(w + 2400768);
  int*   cursor  = (int*)(w + 2800896);
  int*   cursor2 = (int*)(w + 3201024);
  int*   bsum    = (int*)(w + 3601152);
  int*   bsum2   = (int*)(w + 3601664);
  int*   cntg    = (int*)(w + 3602176);
  float* invc    = (float*)(w + 3602432);
  float* ps      = (float*)(w + 3602688);
  float* pas     = (float*)(w + 3602944);
  float* T1      = (float*)(w + 3603200);
  float* Wp      = (float*)(w + 3668736);
  float* c0      = (float*)(w + 3734272);
  float* c1      = (float*)(w + 3734784);
  float* Cbuf    = (float*)(w + 3735296);
  int*   csr_r   = (int*)(w + 3768064);
  float* csr_n   = (float*)(w + 6328064);
  int*   csr2_c  = (int*)(w + 8888064);
  float* csr2_n  = (float*)(w + 11448064);
  float* part    = (float*)(w + 14008064);   // 1024*8192*4 = 33.6 MB
  float* yA      = (float*)(w + 47562496);   // N*64 f32
  float* yB      = (float*)(w + 73162496);   // N*64 f32  (ends ~98.8 MB)

  int nb_n = (N_NODES + 255) / 256;
  int nb_e = (N_EDGES + 255) / 256;

  k_init <<<nb_n, 256, 0, stream>>>(counts, counts2);
  k_count<<<nb_e, 256, 0, stream>>>(row, col, counts, counts2);
  // col-CSR scan
  k_scan1<<<NBLK, 256, 0, stream>>>(counts, bsum);
  k_scan2<<<1, 64, 0, stream>>>(bsum);
  k_scan3<<<NBLK, 256, 0, stream>>>(counts, bsum, offs, cursor);
  // row-CSR scan
  k_scan1<<<NBLK, 256, 0, stream>>>(counts2, bsum2);
  k_scan2<<<1, 64, 0, stream>>>(bsum2);
  k_scan3<<<NBLK, 256, 0, stream>>>(counts2, bsum2, offs2, cursor2);

  k_fill <<<nb_e, 256, 0, stream>>>(row, col, ew, cursor, csr_r, csr_n);
  k_dinv <<<nb_n, 256, 0, stream>>>(offs, csr_n, dinv);
  k_norm <<<nb_n, 256, 0, stream>>>(offs, csr_r, dinv, csr_n);
  k_fill2<<<nb_e, 256, 0, stream>>>(row, col, ew, dinv, cursor2, csr2_c, csr2_n);

  k_cntg <<<1, 64, 0, stream>>>(batch, cntg, invc);
  k_pinit<<<2048, 256, 0, stream>>>(batch, invc, yA);

  k_s    <<<nb_n, 256, 0, stream>>>(offs, csr_n, dinv, s_);
  k_as   <<<nb_n, 256, 0, stream>>>(offs, csr_r, csr_n, dinv, s_, as_);
  k_psum <<<N_GRAPHS, 256, 0, stream>>>(batch, invc, s_, as_, ps, pas);

  int nb_y = (N_NODES + AGG_NPB - 1) / AGG_NPB;
  k_yagg<<<nb_y, 256, 0, stream>>>(yA, offs2, csr2_c, csr2_n, dinv, yB);  // y1
  k_yagg<<<nb_y, 256, 0, stream>>>(yB, offs2, csr2_c, csr2_n, dinv, yA);  // y2
  k_yagg<<<nb_y, 256, 0, stream>>>(yA, offs2, csr2_c, csr2_n, dinv, yB);  // y3

  k_mm128<<<WIDTH, WIDTH, 0, stream>>>(Ws + 1 * WIDTH * WIDTH, Ws + 2 * WIDTH * WIDTH, T1);
  k_mm128<<<WIDTH, WIDTH, 0, stream>>>(Ws + 0 * WIDTH * WIDTH, T1, Wp);
  k_c01  <<<1, WIDTH, 0, stream>>>(bs, T1, bs + WIDTH, Ws + 2 * WIDTH * WIDTH, c0, c1);

  k_contract<<<CB_NB, 256, 0, stream>>>(x, yB, part);
  k_reduceC <<<32, 256, 0, stream>>>(part, Cbuf);
  k_out     <<<N_GRAPHS, WIDTH, 0, stream>>>(Cbuf, Wp, c0, c1, ps, pas, cntg,
                                             bs + 2 * WIDTH, out);
}

// Round 8
// 416.270 us; speedup vs baseline: 1.7003x; 1.7003x over previous
//
#include <hip/hip_runtime.h>
#include <cstddef>

#define N_NODES  100000
#define N_EDGES  640000
#define WIDTH    128
#define LAYERS   3
#define N_GRAPHS 64

#define SCAN_CHUNK 1024
#define NBLK ((N_NODES + SCAN_CHUNK - 1) / SCAN_CHUNK)  // 98

// ---------------- setup kernels ----------------

__global__ void k_init(int* __restrict__ counts, int* __restrict__ counts2) {
  int i = blockIdx.x * blockDim.x + threadIdx.x;
  if (i < N_NODES) { counts[i] = 0; counts2[i] = 0; }
}

// count in-degree (col) and out-degree (row)
__global__ void k_count(const int* __restrict__ row, const int* __restrict__ col,
                        int* __restrict__ counts, int* __restrict__ counts2) {
  int e = blockIdx.x * blockDim.x + threadIdx.x;
  if (e < N_EDGES) {
    atomicAdd(&counts[col[e]], 1);
    atomicAdd(&counts2[row[e]], 1);
  }
}

__global__ void k_scan1(const int* __restrict__ counts, int* __restrict__ bsum) {
  __shared__ int sd[256];
  int t = threadIdx.x;
  int base = blockIdx.x * SCAN_CHUNK;
  int s = 0;
  for (int j = t; j < SCAN_CHUNK; j += 256) {
    int idx = base + j;
    if (idx < N_NODES) s += counts[idx];
  }
  sd[t] = s; __syncthreads();
  for (int off = 128; off > 0; off >>= 1) {
    if (t < off) sd[t] += sd[t + off];
    __syncthreads();
  }
  if (t == 0) bsum[blockIdx.x] = sd[0];
}

__global__ void k_scan2(int* __restrict__ bsum) {
  if (threadIdx.x == 0 && blockIdx.x == 0) {
    int acc = 0;
    for (int i = 0; i < NBLK; i++) { int v = bsum[i]; bsum[i] = acc; acc += v; }
  }
}

__global__ void k_scan3(const int* __restrict__ counts, const int* __restrict__ bsum,
                        int* __restrict__ offs, int* __restrict__ cursor) {
  __shared__ int sd[256];
  int t = threadIdx.x;
  int base = blockIdx.x * SCAN_CHUNK;
  int idx0 = base + t * 4;
  int v0 = (idx0 + 0 < N_NODES) ? counts[idx0 + 0] : 0;
  int v1 = (idx0 + 1 < N_NODES) ? counts[idx0 + 1] : 0;
  int v2 = (idx0 + 2 < N_NODES) ? counts[idx0 + 2] : 0;
  int v3 = (idx0 + 3 < N_NODES) ? counts[idx0 + 3] : 0;
  int s = v0 + v1 + v2 + v3;
  sd[t] = s; __syncthreads();
  for (int off = 1; off < 256; off <<= 1) {
    int val = (t >= off) ? sd[t - off] : 0;
    __syncthreads();
    sd[t] += val;
    __syncthreads();
  }
  int e0 = sd[t] - s + bsum[blockIdx.x];
  if (idx0 + 0 < N_NODES) { offs[idx0 + 0] = e0; cursor[idx0 + 0] = e0; } e0 += v0;
  if (idx0 + 1 < N_NODES) { offs[idx0 + 1] = e0; cursor[idx0 + 1] = e0; } e0 += v1;
  if (idx0 + 2 < N_NODES) { offs[idx0 + 2] = e0; cursor[idx0 + 2] = e0; } e0 += v2;
  if (idx0 + 3 < N_NODES) { offs[idx0 + 3] = e0; cursor[idx0 + 3] = e0; } e0 += v3;
  if (blockIdx.x == NBLK - 1 && t == 255) offs[N_NODES] = e0;
}

// col-CSR fill with raw edge weight (for degree)
__global__ void k_fill(const int* __restrict__ row, const int* __restrict__ col,
                       const float* __restrict__ ew, int* __restrict__ cursor,
                       int* __restrict__ csr_r, float* __restrict__ csr_w) {
  int e = blockIdx.x * blockDim.x + threadIdx.x;
  if (e < N_EDGES) {
    int c = col[e];
    int slot = atomicAdd(&cursor[c], 1);
    csr_r[slot] = row[e];
    csr_w[slot] = ew[e];
  }
}

// deg[v] = 2 + sum incoming w; dinv = rsqrt
__global__ void k_dinv(const int* __restrict__ offs, const float* __restrict__ csr_w,
                       float* __restrict__ dinv) {
  int v = blockIdx.x * blockDim.x + threadIdx.x;
  if (v < N_NODES) {
    int s0 = offs[v], s1 = offs[v + 1];
    float d = 2.0f;
    for (int s = s0; s < s1; s++) d += csr_w[s];
    dinv[v] = (d > 0.0f) ? 1.0f / sqrtf(d) : 0.0f;
  }
}

// csr_n[slot] <- dinv[row]*w*dinv[col]  (col-CSR)
__global__ void k_norm(const int* __restrict__ offs, const int* __restrict__ csr_r,
                       const float* __restrict__ dinv, float* __restrict__ csr_w) {
  int v = blockIdx.x * blockDim.x + threadIdx.x;
  if (v < N_NODES) {
    float dv = dinv[v];
    int s0 = offs[v], s1 = offs[v + 1];
    for (int s = s0; s < s1; s++) csr_w[s] = dinv[csr_r[s]] * csr_w[s] * dv;
  }
}

// row-CSR fill, directly normalized (dinv ready)
__global__ void k_fill2(const int* __restrict__ row, const int* __restrict__ col,
                        const float* __restrict__ ew, const float* __restrict__ dinv,
                        int* __restrict__ cursor2,
                        int* __restrict__ csr2_c, float* __restrict__ csr2_n) {
  int e = blockIdx.x * blockDim.x + threadIdx.x;
  if (e < N_EDGES) {
    int r = row[e], c = col[e];
    int slot = atomicAdd(&cursor2[r], 1);
    csr2_c[slot] = c;
    csr2_n[slot] = dinv[r] * ew[e] * dinv[c];
  }
}

__device__ __forceinline__ int lbound(const int* __restrict__ batch, int key) {
  int lo = 0, hi = N_NODES;
  while (lo < hi) { int m = (lo + hi) >> 1; if (batch[m] < key) lo = m + 1; else hi = m; }
  return lo;
}

// per-graph counts + 1/max(cnt,1)
__global__ void k_cntg(const int* __restrict__ batch, int* __restrict__ cntg,
                       float* __restrict__ invc) {
  int g = threadIdx.x;
  if (g < N_GRAPHS) {
    int lb = lbound(batch, g), ub = lbound(batch, g + 1);
    int c = ub - lb;
    cntg[g] = c;
    invc[g] = 1.0f / (float)max(c, 1);
  }
}

// p[v][g] = (batch[v]==g) * invc[g]   (P^T, N x 64 f32)
__global__ void k_pinit(const int* __restrict__ batch, const float* __restrict__ invc,
                        float* __restrict__ p) {
  const int total = N_NODES * 16;   // float4 count
  for (int i = blockIdx.x * blockDim.x + threadIdx.x; i < total;
       i += gridDim.x * blockDim.x) {
    int v = i >> 4, q = i & 15;
    int b = batch[v];
    float f[4];
#pragma unroll
    for (int k = 0; k < 4; k++) f[k] = (q * 4 + k == b) ? invc[b] : 0.0f;
    *(float4*)(p + (size_t)v * 64 + q * 4) = make_float4(f[0], f[1], f[2], f[3]);
  }
}

// s[v] = (A*1)[v] = 2*dinv^2 + sum of incoming norms (col-CSR)
__global__ void k_s(const int* __restrict__ offs, const float* __restrict__ csr_n,
                    const float* __restrict__ dinv, float* __restrict__ s_) {
  int v = blockIdx.x * blockDim.x + threadIdx.x;
  if (v < N_NODES) {
    float dv = dinv[v];
    float a = 2.0f * dv * dv;
    int s0 = offs[v], s1 = offs[v + 1];
    for (int s = s0; s < s1; s++) a += csr_n[s];
    s_[v] = a;
  }
}

// as[v] = (A*s)[v] = 2*dinv^2*s[v] + sum norm*s[row]
__global__ void k_as(const int* __restrict__ offs, const int* __restrict__ csr_r,
                     const float* __restrict__ csr_n, const float* __restrict__ dinv,
                     const float* __restrict__ s_, float* __restrict__ as_) {
  int v = blockIdx.x * blockDim.x + threadIdx.x;
  if (v < N_NODES) {
    float dv = dinv[v];
    float a = 2.0f * dv * dv * s_[v];
    int s0 = offs[v], s1 = offs[v + 1];
    for (int s = s0; s < s1; s++) a += csr_n[s] * s_[csr_r[s]];
    as_[v] = a;
  }
}

// ps[g] = mean of s over graph g; pas[g] = mean of as
__global__ __launch_bounds__(256) void k_psum(
    const int* __restrict__ batch, const float* __restrict__ invc,
    const float* __restrict__ s_, const float* __restrict__ as_,
    float* __restrict__ ps, float* __restrict__ pas) {
  __shared__ float sd[256];
  int g = blockIdx.x, t = threadIdx.x;
  int lb = lbound(batch, g), ub = lbound(batch, g + 1);
  float a1 = 0.f, a2 = 0.f;
  for (int i = lb + t; i < ub; i += 256) { a1 += s_[i]; a2 += as_[i]; }
  sd[t] = a1; __syncthreads();
  for (int off = 128; off > 0; off >>= 1) { if (t < off) sd[t] += sd[t + off]; __syncthreads(); }
  float tot1 = sd[0]; __syncthreads();
  sd[t] = a2; __syncthreads();
  for (int off = 128; off > 0; off >>= 1) { if (t < off) sd[t] += sd[t + off]; __syncthreads(); }
  if (t == 0) { ps[g] = tot1 * invc[g]; pas[g] = sd[0] * invc[g]; }
}

// ---------------- y-chain: yOut = A^T yIn  (row-CSR gather, 64-wide f32) ----------------
// wave per node: 16 lanes x float4 cover the 64-float row; 4 edge-groups.
// Second gather pair issued only when the window actually has >8 edges.
#define AGG_NPB 4
__global__ __launch_bounds__(256) void k_yagg(
    const float* __restrict__ yin, const int* __restrict__ offs2,
    const int* __restrict__ csr2_c, const float* __restrict__ csr2_n,
    const float* __restrict__ dinv, float* __restrict__ yout) {
  int wave = threadIdx.x >> 6;
  int lane = threadIdx.x & 63;
  int v = blockIdx.x * AGG_NPB + wave;
  if (v >= N_NODES) return;
  int grp = lane >> 4;    // 0..3 edge group
  int q = lane & 15;      // float4 slot (16 x 4 = 64 floats)

  float4 a0 = {0,0,0,0}, a1 = {0,0,0,0}, a2 = {0,0,0,0}, a3 = {0,0,0,0};
  int s0 = offs2[v], s1 = offs2[v + 1];

  for (int c0 = s0; c0 < s1; c0 += 64) {
    int cc = min(64, s1 - c0);
    int   si = (lane < cc) ? csr2_c[c0 + lane] : 0;
    float swv = (lane < cc) ? csr2_n[c0 + lane] : 0.f;
    for (int base = 0; base < cc; base += 16) {
      int e0 = base + grp;
      int e1 = base + 4 + grp;
      float w0 = __shfl(swv, e0); int i0 = __shfl(si, e0);
      float w1 = __shfl(swv, e1); int i1 = __shfl(si, e1);
      float4 v0 = *(const float4*)(yin + (size_t)i0 * 64 + q * 4);
      float4 v1 = *(const float4*)(yin + (size_t)i1 * 64 + q * 4);
      a0.x += w0 * v0.x; a0.y += w0 * v0.y; a0.z += w0 * v0.z; a0.w += w0 * v0.w;
      a1.x += w1 * v1.x; a1.y += w1 * v1.y; a1.z += w1 * v1.z; a1.w += w1 * v1.w;
      if (base + 8 < cc) {   // wave-uniform: skip empty second half
        int e2 = base + 8 + grp;
        int e3 = base + 12 + grp;
        float w2 = __shfl(swv, e2); int i2 = __shfl(si, e2);
        float w3 = __shfl(swv, e3); int i3 = __shfl(si, e3);
        float4 v2 = *(const float4*)(yin + (size_t)i2 * 64 + q * 4);
        float4 v3 = *(const float4*)(yin + (size_t)i3 * 64 + q * 4);
        a2.x += w2 * v2.x; a2.y += w2 * v2.y; a2.z += w2 * v2.z; a2.w += w2 * v2.w;
        a3.x += w3 * v3.x; a3.y += w3 * v3.y; a3.z += w3 * v3.z; a3.w += w3 * v3.w;
      }
    }
  }

  a0.x += a1.x + a2.x + a3.x;
  a0.y += a1.y + a2.y + a3.y;
  a0.z += a1.z + a2.z + a3.z;
  a0.w += a1.w + a2.w + a3.w;
#pragma unroll
  for (int d = 16; d <= 32; d <<= 1) {
    a0.x += __shfl_xor(a0.x, d);
    a0.y += __shfl_xor(a0.y, d);
    a0.z += __shfl_xor(a0.z, d);
    a0.w += __shfl_xor(a0.w, d);
  }

  if (grp == 0) {
    float dv = dinv[v];
    float sc = 2.0f * dv * dv;
    float4 hv = *(const float4*)(yin + (size_t)v * 64 + q * 4);
    float4 r;
    r.x = a0.x + sc * hv.x;
    r.y = a0.y + sc * hv.y;
    r.z = a0.z + sc * hv.z;
    r.w = a0.w + sc * hv.w;
    *(float4*)(yout + (size_t)v * 64 + q * 4) = r;
  }
}

// ---------------- contraction: C[g][j] = sum_v Y3[v][g] * x0[v][j] ----------------
// 512 blocks x 196-node chunks. Wave gh owns g in [gh*16, gh*16+16);
// lane owns j pair. Per node: 1 coalesced float2 x-load, 4 broadcast float4
// y-loads (wave-uniform address), 32 register FMAs. VALU-bound by design.
#define CT_BLOCKS 512
#define CT_CH ((N_NODES + CT_BLOCKS - 1) / CT_BLOCKS)   // 196

__global__ __launch_bounds__(256) void k_contract(
    const float* __restrict__ x0, const float* __restrict__ y3,
    float* __restrict__ part) {
  int b = blockIdx.x, t = threadIdx.x;
  int gh = __builtin_amdgcn_readfirstlane(t >> 6);   // wave id: g-quarter
  int j = (t & 63) * 2;

  float2 acc[16];
#pragma unroll
  for (int i = 0; i < 16; i++) acc[i] = make_float2(0.f, 0.f);

  int start = b * CT_CH, end = min(start + CT_CH, N_NODES);
  for (int v = start; v < end; v++) {
    float2 xv = *(const float2*)(x0 + (size_t)v * WIDTH + j);
    const float4* yr = (const float4*)(y3 + (size_t)v * 64 + gh * 16);
    float4 y0 = yr[0], y1 = yr[1], y2 = yr[2], y3v = yr[3];
    float ys[16] = {y0.x, y0.y, y0.z, y0.w, y1.x, y1.y, y1.z, y1.w,
                    y2.x, y2.y, y2.z, y2.w, y3v.x, y3v.y, y3v.z, y3v.w};
#pragma unroll
    for (int i = 0; i < 16; i++) {
      acc[i].x += ys[i] * xv.x;
      acc[i].y += ys[i] * xv.y;
    }
  }

  float* dst = part + (size_t)b * (N_GRAPHS * WIDTH);
#pragma unroll
  for (int i = 0; i < 16; i++)
    *(float2*)(dst + (gh * 16 + i) * WIDTH + j) = acc[i];
}

__global__ void k_reduceC(const float* __restrict__ part, float* __restrict__ C) {
  int idx = blockIdx.x * blockDim.x + threadIdx.x;   // 0..8191
  if (idx < N_GRAPHS * WIDTH) {
    float a = 0.f;
    for (int b = 0; b < CT_BLOCKS; b++) a += part[(size_t)b * (N_GRAPHS * WIDTH) + idx];
    C[idx] = a;
  }
}

// O = A*B (128x128 f32); block=row, thread=col
__global__ __launch_bounds__(WIDTH) void k_mm128(
    const float* __restrict__ A, const float* __restrict__ B, float* __restrict__ O) {
  __shared__ float Ar[WIDTH];
  int r = blockIdx.x, j = threadIdx.x;
  Ar[j] = A[r * WIDTH + j];
  __syncthreads();
  float a = 0.f;
#pragma unroll 8
  for (int k = 0; k < WIDTH; k++) a += Ar[k] * B[k * WIDTH + j];
  O[r * WIDTH + j] = a;
}

// c0 = b0^T * T1 ; c1 = b1^T * W2
__global__ __launch_bounds__(WIDTH) void k_c01(
    const float* __restrict__ b0, const float* __restrict__ T1,
    const float* __restrict__ b1, const float* __restrict__ W2,
    float* __restrict__ c0, float* __restrict__ c1) {
  __shared__ float s0[WIDTH], s1v[WIDTH];
  int j = threadIdx.x;
  s0[j] = b0[j]; s1v[j] = b1[j];
  __syncthreads();
  float a0 = 0.f, a1 = 0.f;
#pragma unroll 8
  for (int k = 0; k < WIDTH; k++) {
    a0 += s0[k] * T1[k * WIDTH + j];
    a1 += s1v[k] * W2[k * WIDTH + j];
  }
  c0[j] = a0; c1[j] = a1;
}

// out[g][j] = sum_k C[g][k] Wp[k][j] + pas[g]*c0[j] + ps[g]*c1[j] + (cnt>0)*b2[j]
__global__ __launch_bounds__(WIDTH) void k_out(
    const float* __restrict__ C, const float* __restrict__ Wp,
    const float* __restrict__ c0, const float* __restrict__ c1,
    const float* __restrict__ ps, const float* __restrict__ pas,
    const int* __restrict__ cntg, const float* __restrict__ b2,
    float* __restrict__ out) {
  __shared__ float Cr[WIDTH];
  int g = blockIdx.x, j = threadIdx.x;
  Cr[j] = C[g * WIDTH + j];
  __syncthreads();
  float a = pas[g] * c0[j] + ps[g] * c1[j] + ((cntg[g] > 0) ? b2[j] : 0.f);
#pragma unroll 8
  for (int k = 0; k < WIDTH; k++) a += Cr[k] * Wp[k * WIDTH + j];
  out[g * WIDTH + j] = a;
}

// ---------------- launch ----------------

extern "C" void kernel_launch(void* const* d_in, const int* in_sizes, int n_in,
                              void* d_out, int out_size, void* d_ws, size_t ws_size,
                              hipStream_t stream) {
  const float* x   = (const float*)d_in[0];
  const int* row   = (const int*)d_in[1];         // edge_index[0]
  const int* col   = row + N_EDGES;               // edge_index[1]
  const float* ew  = (const float*)d_in[2];
  const int* batch = (const int*)d_in[3];
  const float* Ws  = (const float*)d_in[4];
  const float* bs  = (const float*)d_in[5];
  float* out = (float*)d_out;

  char* w = (char*)d_ws;
  float* dinv    = (float*)(w + 0);
  float* s_      = (float*)(w + 400128);
  float* as_     = (float*)(w + 800256);
  int*   counts  = (int*)(w + 1200384);
  int*   counts2 = (int*)(w + 1600512);
  int*   offs    = (int*)(w + 2000640);
  int*   offs2   = (int*)(w + 2400768);
  int*   cursor  = (int*)(w + 2800896);
  int*   cursor2 = (int*)(w + 3201024);
  int*   bsum    = (int*)(w + 3601152);
  int*   bsum2   = (int*)(w + 3601664);
  int*   cntg    = (int*)(w + 3602176);
  float* invc    = (float*)(w + 3602432);
  float* ps      = (float*)(w + 3602688);
  float* pas     = (float*)(w + 3602944);
  float* T1      = (float*)(w + 3603200);
  float* Wp      = (float*)(w + 3668736);
  float* c0      = (float*)(w + 3734272);
  float* c1      = (float*)(w + 3734784);
  float* Cbuf    = (float*)(w + 3735296);
  int*   csr_r   = (int*)(w + 3768064);
  float* csr_n   = (float*)(w + 6328064);
  int*   csr2_c  = (int*)(w + 8888064);
  float* csr2_n  = (float*)(w + 11448064);
  float* part    = (float*)(w + 14008064);   // 512*8192*4 = 16.8 MB
  float* yA      = (float*)(w + 47562496);   // N*64 f32
  float* yB      = (float*)(w + 73162496);   // N*64 f32

  int nb_n = (N_NODES + 255) / 256;
  int nb_e = (N_EDGES + 255) / 256;

  k_init <<<nb_n, 256, 0, stream>>>(counts, counts2);
  k_count<<<nb_e, 256, 0, stream>>>(row, col, counts, counts2);
  // col-CSR scan
  k_scan1<<<NBLK, 256, 0, stream>>>(counts, bsum);
  k_scan2<<<1, 64, 0, stream>>>(bsum);
  k_scan3<<<NBLK, 256, 0, stream>>>(counts, bsum, offs, cursor);
  // row-CSR scan
  k_scan1<<<NBLK, 256, 0, stream>>>(counts2, bsum2);
  k_scan2<<<1, 64, 0, stream>>>(bsum2);
  k_scan3<<<NBLK, 256, 0, stream>>>(counts2, bsum2, offs2, cursor2);

  k_fill <<<nb_e, 256, 0, stream>>>(row, col, ew, cursor, csr_r, csr_n);
  k_dinv <<<nb_n, 256, 0, stream>>>(offs, csr_n, dinv);
  k_norm <<<nb_n, 256, 0, stream>>>(offs, csr_r, dinv, csr_n);
  k_fill2<<<nb_e, 256, 0, stream>>>(row, col, ew, dinv, cursor2, csr2_c, csr2_n);

  k_cntg <<<1, 64, 0, stream>>>(batch, cntg, invc);
  k_pinit<<<2048, 256, 0, stream>>>(batch, invc, yA);

  k_s    <<<nb_n, 256, 0, stream>>>(offs, csr_n, dinv, s_);
  k_as   <<<nb_n, 256, 0, stream>>>(offs, csr_r, csr_n, dinv, s_, as_);
  k_psum <<<N_GRAPHS, 256, 0, stream>>>(batch, invc, s_, as_, ps, pas);

  int nb_y = (N_NODES + AGG_NPB - 1) / AGG_NPB;
  k_yagg<<<nb_y, 256, 0, stream>>>(yA, offs2, csr2_c, csr2_n, dinv, yB);  // y1
  k_yagg<<<nb_y, 256, 0, stream>>>(yB, offs2, csr2_c, csr2_n, dinv, yA);  // y2
  k_yagg<<<nb_y, 256, 0, stream>>>(yA, offs2, csr2_c, csr2_n, dinv, yB);  // y3

  k_mm128<<<WIDTH, WIDTH, 0, stream>>>(Ws + 1 * WIDTH * WIDTH, Ws + 2 * WIDTH * WIDTH, T1);
  k_mm128<<<WIDTH, WIDTH, 0, stream>>>(Ws + 0 * WIDTH * WIDTH, T1, Wp);
  k_c01  <<<1, WIDTH, 0, stream>>>(bs, T1, bs + WIDTH, Ws + 2 * WIDTH * WIDTH, c0, c1);

  k_contract<<<CT_BLOCKS, 256, 0, stream>>>(x, yB, part);
  k_reduceC <<<32, 256, 0, stream>>>(part, Cbuf);
  k_out     <<<N_GRAPHS, WIDTH, 0, stream>>>(Cbuf, Wp, c0, c1, ps, pas, cntg,
                                             bs + 2 * WIDTH, out);
}

// Round 9
// 414.413 us; speedup vs baseline: 1.7079x; 1.0045x over previous
//
#include <hip/hip_runtime.h>
#include <cstddef>

#define N_NODES  100000
#define N_EDGES  640000
#define WIDTH    128
#define LAYERS   3
#define N_GRAPHS 64

#define SCAN_CHUNK 1024
#define NBLK ((N_NODES + SCAN_CHUNK - 1) / SCAN_CHUNK)  // 98

// ---------------- setup kernels ----------------

__global__ void k_init(int* __restrict__ counts, int* __restrict__ counts2) {
  int i = blockIdx.x * blockDim.x + threadIdx.x;
  if (i < N_NODES) { counts[i] = 0; counts2[i] = 0; }
}

// count in-degree (col) and out-degree (row)
__global__ void k_count(const int* __restrict__ row, const int* __restrict__ col,
                        int* __restrict__ counts, int* __restrict__ counts2) {
  int e = blockIdx.x * blockDim.x + threadIdx.x;
  if (e < N_EDGES) {
    atomicAdd(&counts[col[e]], 1);
    atomicAdd(&counts2[row[e]], 1);
  }
}

__global__ void k_scan1(const int* __restrict__ counts, int* __restrict__ bsum) {
  __shared__ int sd[256];
  int t = threadIdx.x;
  int base = blockIdx.x * SCAN_CHUNK;
  int s = 0;
  for (int j = t; j < SCAN_CHUNK; j += 256) {
    int idx = base + j;
    if (idx < N_NODES) s += counts[idx];
  }
  sd[t] = s; __syncthreads();
  for (int off = 128; off > 0; off >>= 1) {
    if (t < off) sd[t] += sd[t + off];
    __syncthreads();
  }
  if (t == 0) bsum[blockIdx.x] = sd[0];
}

__global__ void k_scan2(int* __restrict__ bsum) {
  if (threadIdx.x == 0 && blockIdx.x == 0) {
    int acc = 0;
    for (int i = 0; i < NBLK; i++) { int v = bsum[i]; bsum[i] = acc; acc += v; }
  }
}

__global__ void k_scan3(const int* __restrict__ counts, const int* __restrict__ bsum,
                        int* __restrict__ offs, int* __restrict__ cursor) {
  __shared__ int sd[256];
  int t = threadIdx.x;
  int base = blockIdx.x * SCAN_CHUNK;
  int idx0 = base + t * 4;
  int v0 = (idx0 + 0 < N_NODES) ? counts[idx0 + 0] : 0;
  int v1 = (idx0 + 1 < N_NODES) ? counts[idx0 + 1] : 0;
  int v2 = (idx0 + 2 < N_NODES) ? counts[idx0 + 2] : 0;
  int v3 = (idx0 + 3 < N_NODES) ? counts[idx0 + 3] : 0;
  int s = v0 + v1 + v2 + v3;
  sd[t] = s; __syncthreads();
  for (int off = 1; off < 256; off <<= 1) {
    int val = (t >= off) ? sd[t - off] : 0;
    __syncthreads();
    sd[t] += val;
    __syncthreads();
  }
  int e0 = sd[t] - s + bsum[blockIdx.x];
  if (idx0 + 0 < N_NODES) { offs[idx0 + 0] = e0; cursor[idx0 + 0] = e0; } e0 += v0;
  if (idx0 + 1 < N_NODES) { offs[idx0 + 1] = e0; cursor[idx0 + 1] = e0; } e0 += v1;
  if (idx0 + 2 < N_NODES) { offs[idx0 + 2] = e0; cursor[idx0 + 2] = e0; } e0 += v2;
  if (idx0 + 3 < N_NODES) { offs[idx0 + 3] = e0; cursor[idx0 + 3] = e0; } e0 += v3;
  if (blockIdx.x == NBLK - 1 && t == 255) offs[N_NODES] = e0;
}

// col-CSR fill with raw edge weight (for degree)
__global__ void k_fill(const int* __restrict__ row, const int* __restrict__ col,
                       const float* __restrict__ ew, int* __restrict__ cursor,
                       int* __restrict__ csr_r, float* __restrict__ csr_w) {
  int e = blockIdx.x * blockDim.x + threadIdx.x;
  if (e < N_EDGES) {
    int c = col[e];
    int slot = atomicAdd(&cursor[c], 1);
    csr_r[slot] = row[e];
    csr_w[slot] = ew[e];
  }
}

// deg[v] = 2 + sum incoming w; dinv = rsqrt
__global__ void k_dinv(const int* __restrict__ offs, const float* __restrict__ csr_w,
                       float* __restrict__ dinv) {
  int v = blockIdx.x * blockDim.x + threadIdx.x;
  if (v < N_NODES) {
    int s0 = offs[v], s1 = offs[v + 1];
    float d = 2.0f;
    for (int s = s0; s < s1; s++) d += csr_w[s];
    dinv[v] = (d > 0.0f) ? 1.0f / sqrtf(d) : 0.0f;
  }
}

// csr_n[slot] <- dinv[row]*w*dinv[col]  (col-CSR); also s_[v] = (A*1)[v]
__global__ void k_norm(const int* __restrict__ offs, const int* __restrict__ csr_r,
                       const float* __restrict__ dinv, float* __restrict__ csr_w,
                       float* __restrict__ s_) {
  int v = blockIdx.x * blockDim.x + threadIdx.x;
  if (v < N_NODES) {
    float dv = dinv[v];
    float a = 2.0f * dv * dv;
    int s0 = offs[v], s1 = offs[v + 1];
    for (int s = s0; s < s1; s++) {
      float nrm = dinv[csr_r[s]] * csr_w[s] * dv;
      csr_w[s] = nrm;
      a += nrm;
    }
    s_[v] = a;
  }
}

// row-CSR fill, directly normalized (dinv ready)
__global__ void k_fill2(const int* __restrict__ row, const int* __restrict__ col,
                        const float* __restrict__ ew, const float* __restrict__ dinv,
                        int* __restrict__ cursor2,
                        int* __restrict__ csr2_c, float* __restrict__ csr2_n) {
  int e = blockIdx.x * blockDim.x + threadIdx.x;
  if (e < N_EDGES) {
    int r = row[e], c = col[e];
    int slot = atomicAdd(&cursor2[r], 1);
    csr2_c[slot] = c;
    csr2_n[slot] = dinv[r] * ew[e] * dinv[c];
  }
}

__device__ __forceinline__ int lbound(const int* __restrict__ batch, int key) {
  int lo = 0, hi = N_NODES;
  while (lo < hi) { int m = (lo + hi) >> 1; if (batch[m] < key) lo = m + 1; else hi = m; }
  return lo;
}

// per-graph counts + 1/max(cnt,1)
__global__ void k_cntg(const int* __restrict__ batch, int* __restrict__ cntg,
                       float* __restrict__ invc) {
  int g = threadIdx.x;
  if (g < N_GRAPHS) {
    int lb = lbound(batch, g), ub = lbound(batch, g + 1);
    int c = ub - lb;
    cntg[g] = c;
    invc[g] = 1.0f / (float)max(c, 1);
  }
}

// p[v][g] = (batch[v]==g) * invc[g]   (P^T, N x 64 f32)
__global__ void k_pinit(const int* __restrict__ batch, const float* __restrict__ invc,
                        float* __restrict__ p) {
  const int total = N_NODES * 16;   // float4 count
  for (int i = blockIdx.x * blockDim.x + threadIdx.x; i < total;
       i += gridDim.x * blockDim.x) {
    int v = i >> 4, q = i & 15;
    int b = batch[v];
    float f[4];
#pragma unroll
    for (int k = 0; k < 4; k++) f[k] = (q * 4 + k == b) ? invc[b] : 0.0f;
    *(float4*)(p + (size_t)v * 64 + q * 4) = make_float4(f[0], f[1], f[2], f[3]);
  }
}

// as[v] = (A*s)[v] = 2*dinv^2*s[v] + sum norm*s[row]
__global__ void k_as(const int* __restrict__ offs, const int* __restrict__ csr_r,
                     const float* __restrict__ csr_n, const float* __restrict__ dinv,
                     const float* __restrict__ s_, float* __restrict__ as_) {
  int v = blockIdx.x * blockDim.x + threadIdx.x;
  if (v < N_NODES) {
    float dv = dinv[v];
    float a = 2.0f * dv * dv * s_[v];
    int s0 = offs[v], s1 = offs[v + 1];
    for (int s = s0; s < s1; s++) a += csr_n[s] * s_[csr_r[s]];
    as_[v] = a;
  }
}

// ps[g] = mean of s over graph g; pas[g] = mean of as
__global__ __launch_bounds__(256) void k_psum(
    const int* __restrict__ batch, const float* __restrict__ invc,
    const float* __restrict__ s_, const float* __restrict__ as_,
    float* __restrict__ ps, float* __restrict__ pas) {
  __shared__ float sd[256];
  int g = blockIdx.x, t = threadIdx.x;
  int lb = lbound(batch, g), ub = lbound(batch, g + 1);
  float a1 = 0.f, a2 = 0.f;
  for (int i = lb + t; i < ub; i += 256) { a1 += s_[i]; a2 += as_[i]; }
  sd[t] = a1; __syncthreads();
  for (int off = 128; off > 0; off >>= 1) { if (t < off) sd[t] += sd[t + off]; __syncthreads(); }
  float tot1 = sd[0]; __syncthreads();
  sd[t] = a2; __syncthreads();
  for (int off = 128; off > 0; off >>= 1) { if (t < off) sd[t] += sd[t + off]; __syncthreads(); }
  if (t == 0) { ps[g] = tot1 * invc[g]; pas[g] = sd[0] * invc[g]; }
}

// ---------------- y-chain: yOut = A^T yIn  (row-CSR gather, 64-wide f32) ----------------
// wave per node: 16 lanes x float4 cover the 64-float row; 4 edge-groups.
// Gather pairs issued only when their edge window is non-empty.
#define AGG_NPB 4
__global__ __launch_bounds__(256) void k_yagg(
    const float* __restrict__ yin, const int* __restrict__ offs2,
    const int* __restrict__ csr2_c, const float* __restrict__ csr2_n,
    const float* __restrict__ dinv, float* __restrict__ yout) {
  int wave = threadIdx.x >> 6;
  int lane = threadIdx.x & 63;
  int v = blockIdx.x * AGG_NPB + wave;
  if (v >= N_NODES) return;
  int vv = __builtin_amdgcn_readfirstlane(v);   // wave-uniform -> SGPR loads
  int grp = lane >> 4;    // 0..3 edge group
  int q = lane & 15;      // float4 slot (16 x 4 = 64 floats)

  // self-row load issued early; broadcast across groups (same addr per q)
  float4 hv = *(const float4*)(yin + (size_t)vv * 64 + q * 4);

  float4 a0 = {0,0,0,0}, a1 = {0,0,0,0}, a2 = {0,0,0,0}, a3 = {0,0,0,0};
  int s0 = offs2[vv], s1 = offs2[vv + 1];

  for (int c0 = s0; c0 < s1; c0 += 64) {
    int cc = min(64, s1 - c0);
    int   si = (lane < cc) ? csr2_c[c0 + lane] : 0;
    float swv = (lane < cc) ? csr2_n[c0 + lane] : 0.f;
    for (int base = 0; base < cc; base += 16) {
      int e0 = base + grp;
      float w0 = __shfl(swv, e0); int i0 = __shfl(si, e0);
      float4 v0 = *(const float4*)(yin + (size_t)i0 * 64 + q * 4);
      a0.x += w0 * v0.x; a0.y += w0 * v0.y; a0.z += w0 * v0.z; a0.w += w0 * v0.w;
      if (base + 4 < cc) {
        int e1 = base + 4 + grp;
        float w1 = __shfl(swv, e1); int i1 = __shfl(si, e1);
        float4 v1 = *(const float4*)(yin + (size_t)i1 * 64 + q * 4);
        a1.x += w1 * v1.x; a1.y += w1 * v1.y; a1.z += w1 * v1.z; a1.w += w1 * v1.w;
      }
      if (base + 8 < cc) {
        int e2 = base + 8 + grp;
        int e3 = base + 12 + grp;
        float w2 = __shfl(swv, e2); int i2 = __shfl(si, e2);
        float w3 = __shfl(swv, e3); int i3 = __shfl(si, e3);
        float4 v2 = *(const float4*)(yin + (size_t)i2 * 64 + q * 4);
        float4 v3 = *(const float4*)(yin + (size_t)i3 * 64 + q * 4);
        a2.x += w2 * v2.x; a2.y += w2 * v2.y; a2.z += w2 * v2.z; a2.w += w2 * v2.w;
        a3.x += w3 * v3.x; a3.y += w3 * v3.y; a3.z += w3 * v3.z; a3.w += w3 * v3.w;
      }
    }
  }

  a0.x += a1.x + a2.x + a3.x;
  a0.y += a1.y + a2.y + a3.y;
  a0.z += a1.z + a2.z + a3.z;
  a0.w += a1.w + a2.w + a3.w;
#pragma unroll
  for (int d = 16; d <= 32; d <<= 1) {
    a0.x += __shfl_xor(a0.x, d);
    a0.y += __shfl_xor(a0.y, d);
    a0.z += __shfl_xor(a0.z, d);
    a0.w += __shfl_xor(a0.w, d);
  }

  if (grp == 0) {
    float dv = dinv[vv];
    float sc = 2.0f * dv * dv;
    float4 r;
    r.x = a0.x + sc * hv.x;
    r.y = a0.y + sc * hv.y;
    r.z = a0.z + sc * hv.z;
    r.w = a0.w + sc * hv.w;
    *(float4*)(yout + (size_t)vv * 64 + q * 4) = r;
  }
}

// ---------------- contraction: C[g][j] = sum_v Y3[v][g] * x0[v][j] ----------------
// 1024 blocks (16 waves/CU), explicit unroll-2: 10 loads in flight per wave.
// Wave gh owns g-quarter; lane owns j pair. x float2 coalesced; y broadcast.
#define CT_BLOCKS 1024
#define CT_CH ((N_NODES + CT_BLOCKS - 1) / CT_BLOCKS)   // 98

__global__ __launch_bounds__(256) void k_contract(
    const float* __restrict__ x0, const float* __restrict__ y3,
    float* __restrict__ part) {
  int b = blockIdx.x, t = threadIdx.x;
  int gh = t >> 6;
  int j = (t & 63) * 2;

  float2 acc[16];
#pragma unroll
  for (int i = 0; i < 16; i++) acc[i] = make_float2(0.f, 0.f);

  int start = b * CT_CH, end = min(start + CT_CH, N_NODES);
  int v = start;
  for (; v + 2 <= end; v += 2) {
    float2 xa = *(const float2*)(x0 + (size_t)v * WIDTH + j);
    float2 xb = *(const float2*)(x0 + (size_t)(v + 1) * WIDTH + j);
    const float4* ya = (const float4*)(y3 + (size_t)v * 64 + gh * 16);
    const float4* yb = (const float4*)(y3 + (size_t)(v + 1) * 64 + gh * 16);
    float4 a0 = ya[0], a1 = ya[1], a2 = ya[2], a3 = ya[3];
    float4 b0 = yb[0], b1 = yb[1], b2 = yb[2], b3 = yb[3];
    float yas[16] = {a0.x, a0.y, a0.z, a0.w, a1.x, a1.y, a1.z, a1.w,
                     a2.x, a2.y, a2.z, a2.w, a3.x, a3.y, a3.z, a3.w};
    float ybs[16] = {b0.x, b0.y, b0.z, b0.w, b1.x, b1.y, b1.z, b1.w,
                     b2.x, b2.y, b2.z, b2.w, b3.x, b3.y, b3.z, b3.w};
#pragma unroll
    for (int i = 0; i < 16; i++) {
      acc[i].x += yas[i] * xa.x;
      acc[i].y += yas[i] * xa.y;
    }
#pragma unroll
    for (int i = 0; i < 16; i++) {
      acc[i].x += ybs[i] * xb.x;
      acc[i].y += ybs[i] * xb.y;
    }
  }
  if (v < end) {
    float2 xa = *(const float2*)(x0 + (size_t)v * WIDTH + j);
    const float4* ya = (const float4*)(y3 + (size_t)v * 64 + gh * 16);
    float4 a0 = ya[0], a1 = ya[1], a2 = ya[2], a3 = ya[3];
    float yas[16] = {a0.x, a0.y, a0.z, a0.w, a1.x, a1.y, a1.z, a1.w,
                     a2.x, a2.y, a2.z, a2.w, a3.x, a3.y, a3.z, a3.w};
#pragma unroll
    for (int i = 0; i < 16; i++) {
      acc[i].x += yas[i] * xa.x;
      acc[i].y += yas[i] * xa.y;
    }
  }

  float* dst = part + (size_t)b * (N_GRAPHS * WIDTH);
#pragma unroll
  for (int i = 0; i < 16; i++)
    *(float2*)(dst + (gh * 16 + i) * WIDTH + j) = acc[i];
}

__global__ void k_reduceC(const float* __restrict__ part, float* __restrict__ C) {
  int idx = blockIdx.x * blockDim.x + threadIdx.x;   // 0..8191
  if (idx < N_GRAPHS * WIDTH) {
    float a = 0.f;
    for (int b = 0; b < CT_BLOCKS; b++) a += part[(size_t)b * (N_GRAPHS * WIDTH) + idx];
    C[idx] = a;
  }
}

// O = A*B (128x128 f32); block=row, thread=col
__global__ __launch_bounds__(WIDTH) void k_mm128(
    const float* __restrict__ A, const float* __restrict__ B, float* __restrict__ O) {
  __shared__ float Ar[WIDTH];
  int r = blockIdx.x, j = threadIdx.x;
  Ar[j] = A[r * WIDTH + j];
  __syncthreads();
  float a = 0.f;
#pragma unroll 8
  for (int k = 0; k < WIDTH; k++) a += Ar[k] * B[k * WIDTH + j];
  O[r * WIDTH + j] = a;
}

// c0 = b0^T * T1 ; c1 = b1^T * W2
__global__ __launch_bounds__(WIDTH) void k_c01(
    const float* __restrict__ b0, const float* __restrict__ T1,
    const float* __restrict__ b1, const float* __restrict__ W2,
    float* __restrict__ c0, float* __restrict__ c1) {
  __shared__ float s0[WIDTH], s1v[WIDTH];
  int j = threadIdx.x;
  s0[j] = b0[j]; s1v[j] = b1[j];
  __syncthreads();
  float a0 = 0.f, a1 = 0.f;
#pragma unroll 8
  for (int k = 0; k < WIDTH; k++) {
    a0 += s0[k] * T1[k * WIDTH + j];
    a1 += s1v[k] * W2[k * WIDTH + j];
  }
  c0[j] = a0; c1[j] = a1;
}

// out[g][j] = sum_k C[g][k] Wp[k][j] + pas[g]*c0[j] + ps[g]*c1[j] + (cnt>0)*b2[j]
__global__ __launch_bounds__(WIDTH) void k_out(
    const float* __restrict__ C, const float* __restrict__ Wp,
    const float* __restrict__ c0, const float* __restrict__ c1,
    const float* __restrict__ ps, const float* __restrict__ pas,
    const int* __restrict__ cntg, const float* __restrict__ b2,
    float* __restrict__ out) {
  __shared__ float Cr[WIDTH];
  int g = blockIdx.x, j = threadIdx.x;
  Cr[j] = C[g * WIDTH + j];
  __syncthreads();
  float a = pas[g] * c0[j] + ps[g] * c1[j] + ((cntg[g] > 0) ? b2[j] : 0.f);
#pragma unroll 8
  for (int k = 0; k < WIDTH; k++) a += Cr[k] * Wp[k * WIDTH + j];
  out[g * WIDTH + j] = a;
}

// ---------------- launch ----------------

extern "C" void kernel_launch(void* const* d_in, const int* in_sizes, int n_in,
                              void* d_out, int out_size, void* d_ws, size_t ws_size,
                              hipStream_t stream) {
  const float* x   = (const float*)d_in[0];
  const int* row   = (const int*)d_in[1];         // edge_index[0]
  const int* col   = row + N_EDGES;               // edge_index[1]
  const float* ew  = (const float*)d_in[2];
  const int* batch = (const int*)d_in[3];
  const float* Ws  = (const float*)d_in[4];
  const float* bs  = (const float*)d_in[5];
  float* out = (float*)d_out;

  char* w = (char*)d_ws;
  float* dinv    = (float*)(w + 0);
  float* s_      = (float*)(w + 400128);
  float* as_     = (float*)(w + 800256);
  int*   counts  = (int*)(w + 1200384);
  int*   counts2 = (int*)(w + 1600512);
  int*   offs    = (int*)(w + 2000640);
  int*   offs2   = (int*)(w + 2400768);
  int*   cursor  = (int*)(w + 2800896);
  int*   cursor2 = (int*)(w + 3201024);
  int*   bsum    = (int*)(w + 3601152);
  int*   bsum2   = (int*)(w + 3601664);
  int*   cntg    = (int*)(w + 3602176);
  float* invc    = (float*)(w + 3602432);
  float* ps      = (float*)(w + 3602688);
  float* pas     = (float*)(w + 3602944);
  float* T1      = (float*)(w + 3603200);
  float* Wp      = (float*)(w + 3668736);
  float* c0      = (float*)(w + 3734272);
  float* c1      = (float*)(w + 3734784);
  float* Cbuf    = (float*)(w + 3735296);
  int*   csr_r   = (int*)(w + 3768064);
  float* csr_n   = (float*)(w + 6328064);
  int*   csr2_c  = (int*)(w + 8888064);
  float* csr2_n  = (float*)(w + 11448064);
  float* part    = (float*)(w + 14008064);   // 1024*8192*4 = 33.5 MB
  float* yA      = (float*)(w + 47562496);   // N*64 f32
  float* yB      = (float*)(w + 73162496);   // N*64 f32

  int nb_n = (N_NODES + 255) / 256;
  int nb_e = (N_EDGES + 255) / 256;

  k_init <<<nb_n, 256, 0, stream>>>(counts, counts2);
  k_count<<<nb_e, 256, 0, stream>>>(row, col, counts, counts2);
  // col-CSR scan
  k_scan1<<<NBLK, 256, 0, stream>>>(counts, bsum);
  k_scan2<<<1, 64, 0, stream>>>(bsum);
  k_scan3<<<NBLK, 256, 0, stream>>>(counts, bsum, offs, cursor);
  // row-CSR scan
  k_scan1<<<NBLK, 256, 0, stream>>>(counts2, bsum2);
  k_scan2<<<1, 64, 0, stream>>>(bsum2);
  k_scan3<<<NBLK, 256, 0, stream>>>(counts2, bsum2, offs2, cursor2);

  k_fill <<<nb_e, 256, 0, stream>>>(row, col, ew, cursor, csr_r, csr_n);
  k_dinv <<<nb_n, 256, 0, stream>>>(offs, csr_n, dinv);
  k_norm <<<nb_n, 256, 0, stream>>>(offs, csr_r, dinv, csr_n, s_);
  k_fill2<<<nb_e, 256, 0, stream>>>(row, col, ew, dinv, cursor2, csr2_c, csr2_n);

  k_cntg <<<1, 64, 0, stream>>>(batch, cntg, invc);
  k_pinit<<<2048, 256, 0, stream>>>(batch, invc, yA);

  k_as   <<<nb_n, 256, 0, stream>>>(offs, csr_r, csr_n, dinv, s_, as_);
  k_psum <<<N_GRAPHS, 256, 0, stream>>>(batch, invc, s_, as_, ps, pas);

  int nb_y = (N_NODES + AGG_NPB - 1) / AGG_NPB;
  k_yagg<<<nb_y, 256, 0, stream>>>(yA, offs2, csr2_c, csr2_n, dinv, yB);  // y1
  k_yagg<<<nb_y, 256, 0, stream>>>(yB, offs2, csr2_c, csr2_n, dinv, yA);  // y2
  k_yagg<<<nb_y, 256, 0, stream>>>(yA, offs2, csr2_c, csr2_n, dinv, yB);  // y3

  k_mm128<<<WIDTH, WIDTH, 0, stream>>>(Ws + 1 * WIDTH * WIDTH, Ws + 2 * WIDTH * WIDTH, T1);
  k_mm128<<<WIDTH, WIDTH, 0, stream>>>(Ws + 0 * WIDTH * WIDTH, T1, Wp);
  k_c01  <<<1, WIDTH, 0, stream>>>(bs, T1, bs + WIDTH, Ws + 2 * WIDTH * WIDTH, c0, c1);

  k_contract<<<CT_BLOCKS, 256, 0, stream>>>(x, yB, part);
  k_reduceC <<<32, 256, 0, stream>>>(part, Cbuf);
  k_out     <<<N_GRAPHS, WIDTH, 0, stream>>>(Cbuf, Wp, c0, c1, ps, pas, cntg,
                                             bs + 2 * WIDTH, out);
}

// Round 10
// 408.843 us; speedup vs baseline: 1.7312x; 1.0136x over previous
//
#include <hip/hip_runtime.h>
#include <cstddef>

#define N_NODES  100000
#define N_EDGES  640000
#define WIDTH    128
#define LAYERS   3
#define N_GRAPHS 64

#define SCAN_CHUNK 1024
#define NBLK ((N_NODES + SCAN_CHUNK - 1) / SCAN_CHUNK)  // 98

#define GLOAD_LDS16(gsrc, ldst) \
  __builtin_amdgcn_global_load_lds( \
      (const __attribute__((address_space(1))) unsigned*)(gsrc), \
      (__attribute__((address_space(3))) unsigned*)(ldst), 16, 0, 0)

// ---------------- setup kernels ----------------

__global__ void k_init(int* __restrict__ counts, int* __restrict__ counts2) {
  int i = blockIdx.x * blockDim.x + threadIdx.x;
  if (i < N_NODES) { counts[i] = 0; counts2[i] = 0; }
}

// count in-degree (col) and out-degree (row)
__global__ void k_count(const int* __restrict__ row, const int* __restrict__ col,
                        int* __restrict__ counts, int* __restrict__ counts2) {
  int e = blockIdx.x * blockDim.x + threadIdx.x;
  if (e < N_EDGES) {
    atomicAdd(&counts[col[e]], 1);
    atomicAdd(&counts2[row[e]], 1);
  }
}

__global__ void k_scan1(const int* __restrict__ counts, int* __restrict__ bsum) {
  __shared__ int sd[256];
  int t = threadIdx.x;
  int base = blockIdx.x * SCAN_CHUNK;
  int s = 0;
  for (int j = t; j < SCAN_CHUNK; j += 256) {
    int idx = base + j;
    if (idx < N_NODES) s += counts[idx];
  }
  sd[t] = s; __syncthreads();
  for (int off = 128; off > 0; off >>= 1) {
    if (t < off) sd[t] += sd[t + off];
    __syncthreads();
  }
  if (t == 0) bsum[blockIdx.x] = sd[0];
}

__global__ void k_scan2(int* __restrict__ bsum) {
  if (threadIdx.x == 0 && blockIdx.x == 0) {
    int acc = 0;
    for (int i = 0; i < NBLK; i++) { int v = bsum[i]; bsum[i] = acc; acc += v; }
  }
}

__global__ void k_scan3(const int* __restrict__ counts, const int* __restrict__ bsum,
                        int* __restrict__ offs, int* __restrict__ cursor) {
  __shared__ int sd[256];
  int t = threadIdx.x;
  int base = blockIdx.x * SCAN_CHUNK;
  int idx0 = base + t * 4;
  int v0 = (idx0 + 0 < N_NODES) ? counts[idx0 + 0] : 0;
  int v1 = (idx0 + 1 < N_NODES) ? counts[idx0 + 1] : 0;
  int v2 = (idx0 + 2 < N_NODES) ? counts[idx0 + 2] : 0;
  int v3 = (idx0 + 3 < N_NODES) ? counts[idx0 + 3] : 0;
  int s = v0 + v1 + v2 + v3;
  sd[t] = s; __syncthreads();
  for (int off = 1; off < 256; off <<= 1) {
    int val = (t >= off) ? sd[t - off] : 0;
    __syncthreads();
    sd[t] += val;
    __syncthreads();
  }
  int e0 = sd[t] - s + bsum[blockIdx.x];
  if (idx0 + 0 < N_NODES) { offs[idx0 + 0] = e0; cursor[idx0 + 0] = e0; } e0 += v0;
  if (idx0 + 1 < N_NODES) { offs[idx0 + 1] = e0; cursor[idx0 + 1] = e0; } e0 += v1;
  if (idx0 + 2 < N_NODES) { offs[idx0 + 2] = e0; cursor[idx0 + 2] = e0; } e0 += v2;
  if (idx0 + 3 < N_NODES) { offs[idx0 + 3] = e0; cursor[idx0 + 3] = e0; } e0 += v3;
  if (blockIdx.x == NBLK - 1 && t == 255) offs[N_NODES] = e0;
}

// col-CSR fill with raw edge weight (for degree)
__global__ void k_fill(const int* __restrict__ row, const int* __restrict__ col,
                       const float* __restrict__ ew, int* __restrict__ cursor,
                       int* __restrict__ csr_r, float* __restrict__ csr_w) {
  int e = blockIdx.x * blockDim.x + threadIdx.x;
  if (e < N_EDGES) {
    int c = col[e];
    int slot = atomicAdd(&cursor[c], 1);
    csr_r[slot] = row[e];
    csr_w[slot] = ew[e];
  }
}

// deg[v] = 2 + sum incoming w; dinv = rsqrt
__global__ void k_dinv(const int* __restrict__ offs, const float* __restrict__ csr_w,
                       float* __restrict__ dinv) {
  int v = blockIdx.x * blockDim.x + threadIdx.x;
  if (v < N_NODES) {
    int s0 = offs[v], s1 = offs[v + 1];
    float d = 2.0f;
    for (int s = s0; s < s1; s++) d += csr_w[s];
    dinv[v] = (d > 0.0f) ? 1.0f / sqrtf(d) : 0.0f;
  }
}

// csr_n[slot] <- dinv[row]*w*dinv[col]  (col-CSR); also s_[v] = (A*1)[v]
__global__ void k_norm(const int* __restrict__ offs, const int* __restrict__ csr_r,
                       const float* __restrict__ dinv, float* __restrict__ csr_w,
                       float* __restrict__ s_) {
  int v = blockIdx.x * blockDim.x + threadIdx.x;
  if (v < N_NODES) {
    float dv = dinv[v];
    float a = 2.0f * dv * dv;
    int s0 = offs[v], s1 = offs[v + 1];
    for (int s = s0; s < s1; s++) {
      float nrm = dinv[csr_r[s]] * csr_w[s] * dv;
      csr_w[s] = nrm;
      a += nrm;
    }
    s_[v] = a;
  }
}

// row-CSR fill, directly normalized (dinv ready)
__global__ void k_fill2(const int* __restrict__ row, const int* __restrict__ col,
                        const float* __restrict__ ew, const float* __restrict__ dinv,
                        int* __restrict__ cursor2,
                        int* __restrict__ csr2_c, float* __restrict__ csr2_n) {
  int e = blockIdx.x * blockDim.x + threadIdx.x;
  if (e < N_EDGES) {
    int r = row[e], c = col[e];
    int slot = atomicAdd(&cursor2[r], 1);
    csr2_c[slot] = c;
    csr2_n[slot] = dinv[r] * ew[e] * dinv[c];
  }
}

__device__ __forceinline__ int lbound(const int* __restrict__ batch, int key) {
  int lo = 0, hi = N_NODES;
  while (lo < hi) { int m = (lo + hi) >> 1; if (batch[m] < key) lo = m + 1; else hi = m; }
  return lo;
}

// per-graph counts + 1/max(cnt,1)
__global__ void k_cntg(const int* __restrict__ batch, int* __restrict__ cntg,
                       float* __restrict__ invc) {
  int g = threadIdx.x;
  if (g < N_GRAPHS) {
    int lb = lbound(batch, g), ub = lbound(batch, g + 1);
    int c = ub - lb;
    cntg[g] = c;
    invc[g] = 1.0f / (float)max(c, 1);
  }
}

// p[v][g] = (batch[v]==g) * invc[g]   (P^T, N x 64 f32)
__global__ void k_pinit(const int* __restrict__ batch, const float* __restrict__ invc,
                        float* __restrict__ p) {
  const int total = N_NODES * 16;   // float4 count
  for (int i = blockIdx.x * blockDim.x + threadIdx.x; i < total;
       i += gridDim.x * blockDim.x) {
    int v = i >> 4, q = i & 15;
    int b = batch[v];
    float f[4];
#pragma unroll
    for (int k = 0; k < 4; k++) f[k] = (q * 4 + k == b) ? invc[b] : 0.0f;
    *(float4*)(p + (size_t)v * 64 + q * 4) = make_float4(f[0], f[1], f[2], f[3]);
  }
}

// as[v] = (A*s)[v] = 2*dinv^2*s[v] + sum norm*s[row]
__global__ void k_as(const int* __restrict__ offs, const int* __restrict__ csr_r,
                     const float* __restrict__ csr_n, const float* __restrict__ dinv,
                     const float* __restrict__ s_, float* __restrict__ as_) {
  int v = blockIdx.x * blockDim.x + threadIdx.x;
  if (v < N_NODES) {
    float dv = dinv[v];
    float a = 2.0f * dv * dv * s_[v];
    int s0 = offs[v], s1 = offs[v + 1];
    for (int s = s0; s < s1; s++) a += csr_n[s] * s_[csr_r[s]];
    as_[v] = a;
  }
}

// ps[g] = mean of s over graph g; pas[g] = mean of as
__global__ __launch_bounds__(256) void k_psum(
    const int* __restrict__ batch, const float* __restrict__ invc,
    const float* __restrict__ s_, const float* __restrict__ as_,
    float* __restrict__ ps, float* __restrict__ pas) {
  __shared__ float sd[256];
  int g = blockIdx.x, t = threadIdx.x;
  int lb = lbound(batch, g), ub = lbound(batch, g + 1);
  float a1 = 0.f, a2 = 0.f;
  for (int i = lb + t; i < ub; i += 256) { a1 += s_[i]; a2 += as_[i]; }
  sd[t] = a1; __syncthreads();
  for (int off = 128; off > 0; off >>= 1) { if (t < off) sd[t] += sd[t + off]; __syncthreads(); }
  float tot1 = sd[0]; __syncthreads();
  sd[t] = a2; __syncthreads();
  for (int off = 128; off > 0; off >>= 1) { if (t < off) sd[t] += sd[t + off]; __syncthreads(); }
  if (t == 0) { ps[g] = tot1 * invc[g]; pas[g] = sd[0] * invc[g]; }
}

// ---------------- y-chain: yOut = A^T yIn  (row-CSR gather, 64-wide f32) ----------------
// wave per node: 16 lanes x float4 cover the 64-float row; 4 edge-groups.
// Gather pairs issued only when their edge window is non-empty.
#define AGG_NPB 4
__global__ __launch_bounds__(256) void k_yagg(
    const float* __restrict__ yin, const int* __restrict__ offs2,
    const int* __restrict__ csr2_c, const float* __restrict__ csr2_n,
    const float* __restrict__ dinv, float* __restrict__ yout) {
  int wave = threadIdx.x >> 6;
  int lane = threadIdx.x & 63;
  int v = blockIdx.x * AGG_NPB + wave;
  if (v >= N_NODES) return;
  int vv = __builtin_amdgcn_readfirstlane(v);   // wave-uniform -> SGPR loads
  int grp = lane >> 4;    // 0..3 edge group
  int q = lane & 15;      // float4 slot (16 x 4 = 64 floats)

  // self-row load issued early; broadcast across groups (same addr per q)
  float4 hv = *(const float4*)(yin + (size_t)vv * 64 + q * 4);

  float4 a0 = {0,0,0,0}, a1 = {0,0,0,0}, a2 = {0,0,0,0}, a3 = {0,0,0,0};
  int s0 = offs2[vv], s1 = offs2[vv + 1];

  for (int c0 = s0; c0 < s1; c0 += 64) {
    int cc = min(64, s1 - c0);
    int   si = (lane < cc) ? csr2_c[c0 + lane] : 0;
    float swv = (lane < cc) ? csr2_n[c0 + lane] : 0.f;
    for (int base = 0; base < cc; base += 16) {
      int e0 = base + grp;
      float w0 = __shfl(swv, e0); int i0 = __shfl(si, e0);
      float4 v0 = *(const float4*)(yin + (size_t)i0 * 64 + q * 4);
      a0.x += w0 * v0.x; a0.y += w0 * v0.y; a0.z += w0 * v0.z; a0.w += w0 * v0.w;
      if (base + 4 < cc) {
        int e1 = base + 4 + grp;
        float w1 = __shfl(swv, e1); int i1 = __shfl(si, e1);
        float4 v1 = *(const float4*)(yin + (size_t)i1 * 64 + q * 4);
        a1.x += w1 * v1.x; a1.y += w1 * v1.y; a1.z += w1 * v1.z; a1.w += w1 * v1.w;
      }
      if (base + 8 < cc) {
        int e2 = base + 8 + grp;
        int e3 = base + 12 + grp;
        float w2 = __shfl(swv, e2); int i2 = __shfl(si, e2);
        float w3 = __shfl(swv, e3); int i3 = __shfl(si, e3);
        float4 v2 = *(const float4*)(yin + (size_t)i2 * 64 + q * 4);
        float4 v3 = *(const float4*)(yin + (size_t)i3 * 64 + q * 4);
        a2.x += w2 * v2.x; a2.y += w2 * v2.y; a2.z += w2 * v2.z; a2.w += w2 * v2.w;
        a3.x += w3 * v3.x; a3.y += w3 * v3.y; a3.z += w3 * v3.z; a3.w += w3 * v3.w;
      }
    }
  }

  a0.x += a1.x + a2.x + a3.x;
  a0.y += a1.y + a2.y + a3.y;
  a0.z += a1.z + a2.z + a3.z;
  a0.w += a1.w + a2.w + a3.w;
#pragma unroll
  for (int d = 16; d <= 32; d <<= 1) {
    a0.x += __shfl_xor(a0.x, d);
    a0.y += __shfl_xor(a0.y, d);
    a0.z += __shfl_xor(a0.z, d);
    a0.w += __shfl_xor(a0.w, d);
  }

  if (grp == 0) {
    float dv = dinv[vv];
    float sc = 2.0f * dv * dv;
    float4 r;
    r.x = a0.x + sc * hv.x;
    r.y = a0.y + sc * hv.y;
    r.z = a0.z + sc * hv.z;
    r.w = a0.w + sc * hv.w;
    *(float4*)(yout + (size_t)vv * 64 + q * 4) = r;
  }
}

// ---------------- contraction: C[g][j] = sum_v Y3[v][g] * x0[v][j] ----------------
// GEMM-style: 64-node chunks staged to LDS via global_load_lds (both slabs are
// contiguous global regions), then LDS-fed FMAs. Accumulators persist across
// grid-stride chunks; one part-write per block. 768 blocks = 3/CU (48KB LDS).
#define CT_BLOCKS 768
#define CT_NCHUNK ((N_NODES + 63) / 64)   // 1563

__global__ __launch_bounds__(256) void k_contract(
    const float* __restrict__ x0, const float* __restrict__ y3,
    float* __restrict__ part) {
  __shared__ __align__(16) float xs[64 * 128];   // 32 KB
  __shared__ __align__(16) float ys[64 * 64];    // 16 KB
  int t = threadIdx.x;
  int w = t >> 6;
  int lane = t & 63;
  int j = lane * 2;

  float2 acc[16];
#pragma unroll
  for (int i = 0; i < 16; i++) acc[i] = make_float2(0.f, 0.f);

  for (int c = blockIdx.x; c < CT_NCHUNK; c += gridDim.x) {
    int cc = min(64, N_NODES - c * 64);
    int bx = cc * 512;   // bytes of x slab
    int by = cc * 256;   // bytes of y slab
    const char* gx = (const char*)(x0 + (size_t)c * 64 * 128);
    const char* gy = (const char*)(y3 + (size_t)c * 64 * 64);
    __syncthreads();     // previous compute done before overwriting LDS
#pragma unroll
    for (int i = 0; i < 8; i++) {
      int off = i * 4096 + t * 16;
      if (off < bx) GLOAD_LDS16(gx + off, (char*)xs + off);
    }
#pragma unroll
    for (int i = 0; i < 4; i++) {
      int off = i * 4096 + t * 16;
      if (off < by) GLOAD_LDS16(gy + off, (char*)ys + off);
    }
    asm volatile("s_waitcnt vmcnt(0)" ::: "memory");
    __syncthreads();

    int v = 0;
    for (; v + 2 <= cc; v += 2) {
      const float4* yra = (const float4*)(ys + v * 64 + w * 16);
      const float4* yrb = (const float4*)(ys + (v + 1) * 64 + w * 16);
      float4 a0 = yra[0], a1 = yra[1], a2 = yra[2], a3 = yra[3];
      float4 b0 = yrb[0], b1 = yrb[1], b2 = yrb[2], b3 = yrb[3];
      float2 xa = *(const float2*)(xs + v * 128 + j);
      float2 xb = *(const float2*)(xs + (v + 1) * 128 + j);
      float yas[16] = {a0.x, a0.y, a0.z, a0.w, a1.x, a1.y, a1.z, a1.w,
                       a2.x, a2.y, a2.z, a2.w, a3.x, a3.y, a3.z, a3.w};
      float ybs[16] = {b0.x, b0.y, b0.z, b0.w, b1.x, b1.y, b1.z, b1.w,
                       b2.x, b2.y, b2.z, b2.w, b3.x, b3.y, b3.z, b3.w};
#pragma unroll
      for (int i = 0; i < 16; i++) {
        acc[i].x += yas[i] * xa.x;
        acc[i].y += yas[i] * xa.y;
      }
#pragma unroll
      for (int i = 0; i < 16; i++) {
        acc[i].x += ybs[i] * xb.x;
        acc[i].y += ybs[i] * xb.y;
      }
    }
    if (v < cc) {
      const float4* yra = (const float4*)(ys + v * 64 + w * 16);
      float4 a0 = yra[0], a1 = yra[1], a2 = yra[2], a3 = yra[3];
      float2 xa = *(const float2*)(xs + v * 128 + j);
      float yas[16] = {a0.x, a0.y, a0.z, a0.w, a1.x, a1.y, a1.z, a1.w,
                       a2.x, a2.y, a2.z, a2.w, a3.x, a3.y, a3.z, a3.w};
#pragma unroll
      for (int i = 0; i < 16; i++) {
        acc[i].x += yas[i] * xa.x;
        acc[i].y += yas[i] * xa.y;
      }
    }
  }

  float* dst = part + (size_t)blockIdx.x * (N_GRAPHS * WIDTH);
#pragma unroll
  for (int i = 0; i < 16; i++)
    *(float2*)(dst + (w * 16 + i) * WIDTH + j) = acc[i];
}

__global__ void k_reduceC(const float* __restrict__ part, float* __restrict__ C) {
  int idx = blockIdx.x * blockDim.x + threadIdx.x;   // 0..8191
  if (idx < N_GRAPHS * WIDTH) {
    float a0 = 0.f, a1 = 0.f, a2 = 0.f, a3 = 0.f;
    for (int b = 0; b + 4 <= CT_BLOCKS; b += 4) {
      a0 += part[(size_t)(b + 0) * (N_GRAPHS * WIDTH) + idx];
      a1 += part[(size_t)(b + 1) * (N_GRAPHS * WIDTH) + idx];
      a2 += part[(size_t)(b + 2) * (N_GRAPHS * WIDTH) + idx];
      a3 += part[(size_t)(b + 3) * (N_GRAPHS * WIDTH) + idx];
    }
    C[idx] = (a0 + a1) + (a2 + a3);
  }
}

// O = A*B (128x128 f32); block=row, thread=col
__global__ __launch_bounds__(WIDTH) void k_mm128(
    const float* __restrict__ A, const float* __restrict__ B, float* __restrict__ O) {
  __shared__ float Ar[WIDTH];
  int r = blockIdx.x, j = threadIdx.x;
  Ar[j] = A[r * WIDTH + j];
  __syncthreads();
  float a = 0.f;
#pragma unroll 8
  for (int k = 0; k < WIDTH; k++) a += Ar[k] * B[k * WIDTH + j];
  O[r * WIDTH + j] = a;
}

// c0 = b0^T * T1 ; c1 = b1^T * W2
__global__ __launch_bounds__(WIDTH) void k_c01(
    const float* __restrict__ b0, const float* __restrict__ T1,
    const float* __restrict__ b1, const float* __restrict__ W2,
    float* __restrict__ c0, float* __restrict__ c1) {
  __shared__ float s0[WIDTH], s1v[WIDTH];
  int j = threadIdx.x;
  s0[j] = b0[j]; s1v[j] = b1[j];
  __syncthreads();
  float a0 = 0.f, a1 = 0.f;
#pragma unroll 8
  for (int k = 0; k < WIDTH; k++) {
    a0 += s0[k] * T1[k * WIDTH + j];
    a1 += s1v[k] * W2[k * WIDTH + j];
  }
  c0[j] = a0; c1[j] = a1;
}

// out[g][j] = sum_k C[g][k] Wp[k][j] + pas[g]*c0[j] + ps[g]*c1[j] + (cnt>0)*b2[j]
__global__ __launch_bounds__(WIDTH) void k_out(
    const float* __restrict__ C, const float* __restrict__ Wp,
    const float* __restrict__ c0, const float* __restrict__ c1,
    const float* __restrict__ ps, const float* __restrict__ pas,
    const int* __restrict__ cntg, const float* __restrict__ b2,
    float* __restrict__ out) {
  __shared__ float Cr[WIDTH];
  int g = blockIdx.x, j = threadIdx.x;
  Cr[j] = C[g * WIDTH + j];
  __syncthreads();
  float a = pas[g] * c0[j] + ps[g] * c1[j] + ((cntg[g] > 0) ? b2[j] : 0.f);
#pragma unroll 8
  for (int k = 0; k < WIDTH; k++) a += Cr[k] * Wp[k * WIDTH + j];
  out[g * WIDTH + j] = a;
}

// ---------------- launch ----------------

extern "C" void kernel_launch(void* const* d_in, const int* in_sizes, int n_in,
                              void* d_out, int out_size, void* d_ws, size_t ws_size,
                              hipStream_t stream) {
  const float* x   = (const float*)d_in[0];
  const int* row   = (const int*)d_in[1];         // edge_index[0]
  const int* col   = row + N_EDGES;               // edge_index[1]
  const float* ew  = (const float*)d_in[2];
  const int* batch = (const int*)d_in[3];
  const float* Ws  = (const float*)d_in[4];
  const float* bs  = (const float*)d_in[5];
  float* out = (float*)d_out;

  char* w = (char*)d_ws;
  float* dinv    = (float*)(w + 0);
  float* s_      = (float*)(w + 400128);
  float* as_     = (float*)(w + 800256);
  int*   counts  = (int*)(w + 1200384);
  int*   counts2 = (int*)(w + 1600512);
  int*   offs    = (int*)(w + 2000640);
  int*   offs2   = (int*)(w + 2400768);
  int*   cursor  = (int*)(w + 2800896);
  int*   cursor2 = (int*)(w + 3201024);
  int*   bsum    = (int*)(w + 3601152);
  int*   bsum2   = (int*)(w + 3601664);
  int*   cntg    = (int*)(w + 3602176);
  float* invc    = (float*)(w + 3602432);
  float* ps      = (float*)(w + 3602688);
  float* pas     = (float*)(w + 3602944);
  float* T1      = (float*)(w + 3603200);
  float* Wp      = (float*)(w + 3668736);
  float* c0      = (float*)(w + 3734272);
  float* c1      = (float*)(w + 3734784);
  float* Cbuf    = (float*)(w + 3735296);
  int*   csr_r   = (int*)(w + 3768064);
  float* csr_n   = (float*)(w + 6328064);
  int*   csr2_c  = (int*)(w + 8888064);
  float* csr2_n  = (float*)(w + 11448064);
  float* part    = (float*)(w + 14008064);   // 768*8192*4 = 25.2 MB
  float* yA      = (float*)(w + 47562496);   // N*64 f32
  float* yB      = (float*)(w + 73162496);   // N*64 f32

  int nb_n = (N_NODES + 255) / 256;
  int nb_e = (N_EDGES + 255) / 256;

  k_init <<<nb_n, 256, 0, stream>>>(counts, counts2);
  k_count<<<nb_e, 256, 0, stream>>>(row, col, counts, counts2);
  // col-CSR scan
  k_scan1<<<NBLK, 256, 0, stream>>>(counts, bsum);
  k_scan2<<<1, 64, 0, stream>>>(bsum);
  k_scan3<<<NBLK, 256, 0, stream>>>(counts, bsum, offs, cursor);
  // row-CSR scan
  k_scan1<<<NBLK, 256, 0, stream>>>(counts2, bsum2);
  k_scan2<<<1, 64, 0, stream>>>(bsum2);
  k_scan3<<<NBLK, 256, 0, stream>>>(counts2, bsum2, offs2, cursor2);

  k_fill <<<nb_e, 256, 0, stream>>>(row, col, ew, cursor, csr_r, csr_n);
  k_dinv <<<nb_n, 256, 0, stream>>>(offs, csr_n, dinv);
  k_norm <<<nb_n, 256, 0, stream>>>(offs, csr_r, dinv, csr_n, s_);
  k_fill2<<<nb_e, 256, 0, stream>>>(row, col, ew, dinv, cursor2, csr2_c, csr2_n);

  k_cntg <<<1, 64, 0, stream>>>(batch, cntg, invc);
  k_pinit<<<2048, 256, 0, stream>>>(batch, invc, yA);

  k_as   <<<nb_n, 256, 0, stream>>>(offs, csr_r, csr_n, dinv, s_, as_);
  k_psum <<<N_GRAPHS, 256, 0, stream>>>(batch, invc, s_, as_, ps, pas);

  int nb_y = (N_NODES + AGG_NPB - 1) / AGG_NPB;
  k_yagg<<<nb_y, 256, 0, stream>>>(yA, offs2, csr2_c, csr2_n, dinv, yB);  // y1
  k_yagg<<<nb_y, 256, 0, stream>>>(yB, offs2, csr2_c, csr2_n, dinv, yA);  // y2
  k_yagg<<<nb_y, 256, 0, stream>>>(yA, offs2, csr2_c, csr2_n, dinv, yB);  // y3

  k_mm128<<<WIDTH, WIDTH, 0, stream>>>(Ws + 1 * WIDTH * WIDTH, Ws + 2 * WIDTH * WIDTH, T1);
  k_mm128<<<WIDTH, WIDTH, 0, stream>>>(Ws + 0 * WIDTH * WIDTH, T1, Wp);
  k_c01  <<<1, WIDTH, 0, stream>>>(bs, T1, bs + WIDTH, Ws + 2 * WIDTH * WIDTH, c0, c1);

  k_contract<<<CT_BLOCKS, 256, 0, stream>>>(x, yB, part);
  k_reduceC <<<32, 256, 0, stream>>>(part, Cbuf);
  k_out     <<<N_GRAPHS, WIDTH, 0, stream>>>(Cbuf, Wp, c0, c1, ps, pas, cntg,
                                             bs + 2 * WIDTH, out);
}

// Round 11
// 353.373 us; speedup vs baseline: 2.0029x; 1.1570x over previous
//
#include <hip/hip_runtime.h>
#include <cstddef>

#define N_NODES  100000
#define N_EDGES  640000
#define WIDTH    128
#define LAYERS   3
#define N_GRAPHS 64

#define SCAN_CHUNK 1024
#define NBLK ((N_NODES + SCAN_CHUNK - 1) / SCAN_CHUNK)  // 98

#define GLOAD_LDS16(gsrc, ldst) \
  __builtin_amdgcn_global_load_lds( \
      (const __attribute__((address_space(1))) unsigned*)(gsrc), \
      (__attribute__((address_space(3))) unsigned*)(ldst), 16, 0, 0)

// ---------------- setup kernels ----------------

__global__ void k_init(int* __restrict__ counts, int* __restrict__ counts2) {
  int i = blockIdx.x * blockDim.x + threadIdx.x;
  if (i < N_NODES) { counts[i] = 0; counts2[i] = 0; }
}

// count in-degree (col) and out-degree (row)
__global__ void k_count(const int* __restrict__ row, const int* __restrict__ col,
                        int* __restrict__ counts, int* __restrict__ counts2) {
  int e = blockIdx.x * blockDim.x + threadIdx.x;
  if (e < N_EDGES) {
    atomicAdd(&counts[col[e]], 1);
    atomicAdd(&counts2[row[e]], 1);
  }
}

__global__ void k_scan1(const int* __restrict__ counts, int* __restrict__ bsum) {
  __shared__ int sd[256];
  int t = threadIdx.x;
  int base = blockIdx.x * SCAN_CHUNK;
  int s = 0;
  for (int j = t; j < SCAN_CHUNK; j += 256) {
    int idx = base + j;
    if (idx < N_NODES) s += counts[idx];
  }
  sd[t] = s; __syncthreads();
  for (int off = 128; off > 0; off >>= 1) {
    if (t < off) sd[t] += sd[t + off];
    __syncthreads();
  }
  if (t == 0) bsum[blockIdx.x] = sd[0];
}

__global__ void k_scan2(int* __restrict__ bsum) {
  if (threadIdx.x == 0 && blockIdx.x == 0) {
    int acc = 0;
    for (int i = 0; i < NBLK; i++) { int v = bsum[i]; bsum[i] = acc; acc += v; }
  }
}

__global__ void k_scan3(const int* __restrict__ counts, const int* __restrict__ bsum,
                        int* __restrict__ offs, int* __restrict__ cursor) {
  __shared__ int sd[256];
  int t = threadIdx.x;
  int base = blockIdx.x * SCAN_CHUNK;
  int idx0 = base + t * 4;
  int v0 = (idx0 + 0 < N_NODES) ? counts[idx0 + 0] : 0;
  int v1 = (idx0 + 1 < N_NODES) ? counts[idx0 + 1] : 0;
  int v2 = (idx0 + 2 < N_NODES) ? counts[idx0 + 2] : 0;
  int v3 = (idx0 + 3 < N_NODES) ? counts[idx0 + 3] : 0;
  int s = v0 + v1 + v2 + v3;
  sd[t] = s; __syncthreads();
  for (int off = 1; off < 256; off <<= 1) {
    int val = (t >= off) ? sd[t - off] : 0;
    __syncthreads();
    sd[t] += val;
    __syncthreads();
  }
  int e0 = sd[t] - s + bsum[blockIdx.x];
  if (idx0 + 0 < N_NODES) { offs[idx0 + 0] = e0; cursor[idx0 + 0] = e0; } e0 += v0;
  if (idx0 + 1 < N_NODES) { offs[idx0 + 1] = e0; cursor[idx0 + 1] = e0; } e0 += v1;
  if (idx0 + 2 < N_NODES) { offs[idx0 + 2] = e0; cursor[idx0 + 2] = e0; } e0 += v2;
  if (idx0 + 3 < N_NODES) { offs[idx0 + 3] = e0; cursor[idx0 + 3] = e0; } e0 += v3;
  if (blockIdx.x == NBLK - 1 && t == 255) offs[N_NODES] = e0;
}

// col-CSR fill with raw edge weight (for degree)
__global__ void k_fill(const int* __restrict__ row, const int* __restrict__ col,
                       const float* __restrict__ ew, int* __restrict__ cursor,
                       int* __restrict__ csr_r, float* __restrict__ csr_w) {
  int e = blockIdx.x * blockDim.x + threadIdx.x;
  if (e < N_EDGES) {
    int c = col[e];
    int slot = atomicAdd(&cursor[c], 1);
    csr_r[slot] = row[e];
    csr_w[slot] = ew[e];
  }
}

// deg[v] = 2 + sum incoming w; dinv = rsqrt
__global__ void k_dinv(const int* __restrict__ offs, const float* __restrict__ csr_w,
                       float* __restrict__ dinv) {
  int v = blockIdx.x * blockDim.x + threadIdx.x;
  if (v < N_NODES) {
    int s0 = offs[v], s1 = offs[v + 1];
    float d = 2.0f;
    for (int s = s0; s < s1; s++) d += csr_w[s];
    dinv[v] = (d > 0.0f) ? 1.0f / sqrtf(d) : 0.0f;
  }
}

// csr_n[slot] <- dinv[row]*w*dinv[col]  (col-CSR); also s_[v] = (A*1)[v]
__global__ void k_norm(const int* __restrict__ offs, const int* __restrict__ csr_r,
                       const float* __restrict__ dinv, float* __restrict__ csr_w,
                       float* __restrict__ s_) {
  int v = blockIdx.x * blockDim.x + threadIdx.x;
  if (v < N_NODES) {
    float dv = dinv[v];
    float a = 2.0f * dv * dv;
    int s0 = offs[v], s1 = offs[v + 1];
    for (int s = s0; s < s1; s++) {
      float nrm = dinv[csr_r[s]] * csr_w[s] * dv;
      csr_w[s] = nrm;
      a += nrm;
    }
    s_[v] = a;
  }
}

// row-CSR fill, directly normalized (dinv ready)
__global__ void k_fill2(const int* __restrict__ row, const int* __restrict__ col,
                        const float* __restrict__ ew, const float* __restrict__ dinv,
                        int* __restrict__ cursor2,
                        int* __restrict__ csr2_c, float* __restrict__ csr2_n) {
  int e = blockIdx.x * blockDim.x + threadIdx.x;
  if (e < N_EDGES) {
    int r = row[e], c = col[e];
    int slot = atomicAdd(&cursor2[r], 1);
    csr2_c[slot] = c;
    csr2_n[slot] = dinv[r] * ew[e] * dinv[c];
  }
}

__device__ __forceinline__ int lbound(const int* __restrict__ batch, int key) {
  int lo = 0, hi = N_NODES;
  while (lo < hi) { int m = (lo + hi) >> 1; if (batch[m] < key) lo = m + 1; else hi = m; }
  return lo;
}

// per-graph counts + 1/max(cnt,1)
__global__ void k_cntg(const int* __restrict__ batch, int* __restrict__ cntg,
                       float* __restrict__ invc) {
  int g = threadIdx.x;
  if (g < N_GRAPHS) {
    int lb = lbound(batch, g), ub = lbound(batch, g + 1);
    int c = ub - lb;
    cntg[g] = c;
    invc[g] = 1.0f / (float)max(c, 1);
  }
}

// p[v][g] = (batch[v]==g) * invc[g]   (P^T, N x 64 f32)
__global__ void k_pinit(const int* __restrict__ batch, const float* __restrict__ invc,
                        float* __restrict__ p) {
  const int total = N_NODES * 16;   // float4 count
  for (int i = blockIdx.x * blockDim.x + threadIdx.x; i < total;
       i += gridDim.x * blockDim.x) {
    int v = i >> 4, q = i & 15;
    int b = batch[v];
    float f[4];
#pragma unroll
    for (int k = 0; k < 4; k++) f[k] = (q * 4 + k == b) ? invc[b] : 0.0f;
    *(float4*)(p + (size_t)v * 64 + q * 4) = make_float4(f[0], f[1], f[2], f[3]);
  }
}

// as[v] = (A*s)[v] = 2*dinv^2*s[v] + sum norm*s[row]
__global__ void k_as(const int* __restrict__ offs, const int* __restrict__ csr_r,
                     const float* __restrict__ csr_n, const float* __restrict__ dinv,
                     const float* __restrict__ s_, float* __restrict__ as_) {
  int v = blockIdx.x * blockDim.x + threadIdx.x;
  if (v < N_NODES) {
    float dv = dinv[v];
    float a = 2.0f * dv * dv * s_[v];
    int s0 = offs[v], s1 = offs[v + 1];
    for (int s = s0; s < s1; s++) a += csr_n[s] * s_[csr_r[s]];
    as_[v] = a;
  }
}

// ps[g] = mean of s over graph g; pas[g] = mean of as
__global__ __launch_bounds__(256) void k_psum(
    const int* __restrict__ batch, const float* __restrict__ invc,
    const float* __restrict__ s_, const float* __restrict__ as_,
    float* __restrict__ ps, float* __restrict__ pas) {
  __shared__ float sd[256];
  int g = blockIdx.x, t = threadIdx.x;
  int lb = lbound(batch, g), ub = lbound(batch, g + 1);
  float a1 = 0.f, a2 = 0.f;
  for (int i = lb + t; i < ub; i += 256) { a1 += s_[i]; a2 += as_[i]; }
  sd[t] = a1; __syncthreads();
  for (int off = 128; off > 0; off >>= 1) { if (t < off) sd[t] += sd[t + off]; __syncthreads(); }
  float tot1 = sd[0]; __syncthreads();
  sd[t] = a2; __syncthreads();
  for (int off = 128; off > 0; off >>= 1) { if (t < off) sd[t] += sd[t + off]; __syncthreads(); }
  if (t == 0) { ps[g] = tot1 * invc[g]; pas[g] = sd[0] * invc[g]; }
}

// ---------------- y-chain: yOut = A^T yIn  (row-CSR gather, 64-wide f32) ----------------
// wave per node: 16 lanes x float4 cover the 64-float row; 4 edge-groups.
// Gather pairs issued only when their edge window is non-empty.
#define AGG_NPB 4
__global__ __launch_bounds__(256) void k_yagg(
    const float* __restrict__ yin, const int* __restrict__ offs2,
    const int* __restrict__ csr2_c, const float* __restrict__ csr2_n,
    const float* __restrict__ dinv, float* __restrict__ yout) {
  int wave = threadIdx.x >> 6;
  int lane = threadIdx.x & 63;
  int v = blockIdx.x * AGG_NPB + wave;
  if (v >= N_NODES) return;
  int vv = __builtin_amdgcn_readfirstlane(v);   // wave-uniform -> SGPR loads
  int grp = lane >> 4;    // 0..3 edge group
  int q = lane & 15;      // float4 slot (16 x 4 = 64 floats)

  // self-row load issued early; broadcast across groups (same addr per q)
  float4 hv = *(const float4*)(yin + (size_t)vv * 64 + q * 4);

  float4 a0 = {0,0,0,0}, a1 = {0,0,0,0}, a2 = {0,0,0,0}, a3 = {0,0,0,0};
  int s0 = offs2[vv], s1 = offs2[vv + 1];

  for (int c0 = s0; c0 < s1; c0 += 64) {
    int cc = min(64, s1 - c0);
    int   si = (lane < cc) ? csr2_c[c0 + lane] : 0;
    float swv = (lane < cc) ? csr2_n[c0 + lane] : 0.f;
    for (int base = 0; base < cc; base += 16) {
      int e0 = base + grp;
      float w0 = __shfl(swv, e0); int i0 = __shfl(si, e0);
      float4 v0 = *(const float4*)(yin + (size_t)i0 * 64 + q * 4);
      a0.x += w0 * v0.x; a0.y += w0 * v0.y; a0.z += w0 * v0.z; a0.w += w0 * v0.w;
      if (base + 4 < cc) {
        int e1 = base + 4 + grp;
        float w1 = __shfl(swv, e1); int i1 = __shfl(si, e1);
        float4 v1 = *(const float4*)(yin + (size_t)i1 * 64 + q * 4);
        a1.x += w1 * v1.x; a1.y += w1 * v1.y; a1.z += w1 * v1.z; a1.w += w1 * v1.w;
      }
      if (base + 8 < cc) {
        int e2 = base + 8 + grp;
        int e3 = base + 12 + grp;
        float w2 = __shfl(swv, e2); int i2 = __shfl(si, e2);
        float w3 = __shfl(swv, e3); int i3 = __shfl(si, e3);
        float4 v2 = *(const float4*)(yin + (size_t)i2 * 64 + q * 4);
        float4 v3 = *(const float4*)(yin + (size_t)i3 * 64 + q * 4);
        a2.x += w2 * v2.x; a2.y += w2 * v2.y; a2.z += w2 * v2.z; a2.w += w2 * v2.w;
        a3.x += w3 * v3.x; a3.y += w3 * v3.y; a3.z += w3 * v3.z; a3.w += w3 * v3.w;
      }
    }
  }

  a0.x += a1.x + a2.x + a3.x;
  a0.y += a1.y + a2.y + a3.y;
  a0.z += a1.z + a2.z + a3.z;
  a0.w += a1.w + a2.w + a3.w;
#pragma unroll
  for (int d = 16; d <= 32; d <<= 1) {
    a0.x += __shfl_xor(a0.x, d);
    a0.y += __shfl_xor(a0.y, d);
    a0.z += __shfl_xor(a0.z, d);
    a0.w += __shfl_xor(a0.w, d);
  }

  if (grp == 0) {
    float dv = dinv[vv];
    float sc = 2.0f * dv * dv;
    float4 r;
    r.x = a0.x + sc * hv.x;
    r.y = a0.y + sc * hv.y;
    r.z = a0.z + sc * hv.z;
    r.w = a0.w + sc * hv.w;
    *(float4*)(yout + (size_t)vv * 64 + q * 4) = r;
  }
}

// ---------------- contraction: C[g][j] = sum_v Y3[v][g] * x0[v][j] ----------------
// GEMM-style: 64-node chunks staged to LDS via global_load_lds, then LDS-fed
// FMAs. Accumulators persist across grid-stride chunks. 768 blocks = 3/CU.
#define CT_BLOCKS 768
#define CT_NCHUNK ((N_NODES + 63) / 64)   // 1563

__global__ __launch_bounds__(256) void k_contract(
    const float* __restrict__ x0, const float* __restrict__ y3,
    float* __restrict__ part) {
  __shared__ __align__(16) float xs[64 * 128];   // 32 KB
  __shared__ __align__(16) float ys[64 * 64];    // 16 KB
  int t = threadIdx.x;
  int w = t >> 6;
  int lane = t & 63;
  int j = lane * 2;

  float2 acc[16];
#pragma unroll
  for (int i = 0; i < 16; i++) acc[i] = make_float2(0.f, 0.f);

  for (int c = blockIdx.x; c < CT_NCHUNK; c += gridDim.x) {
    int cc = min(64, N_NODES - c * 64);
    int bx = cc * 512;   // bytes of x slab
    int by = cc * 256;   // bytes of y slab
    const char* gx = (const char*)(x0 + (size_t)c * 64 * 128);
    const char* gy = (const char*)(y3 + (size_t)c * 64 * 64);
    __syncthreads();     // previous compute done before overwriting LDS
#pragma unroll
    for (int i = 0; i < 8; i++) {
      int off = i * 4096 + t * 16;
      if (off < bx) GLOAD_LDS16(gx + off, (char*)xs + off);
    }
#pragma unroll
    for (int i = 0; i < 4; i++) {
      int off = i * 4096 + t * 16;
      if (off < by) GLOAD_LDS16(gy + off, (char*)ys + off);
    }
    asm volatile("s_waitcnt vmcnt(0)" ::: "memory");
    __syncthreads();

    int v = 0;
    for (; v + 2 <= cc; v += 2) {
      const float4* yra = (const float4*)(ys + v * 64 + w * 16);
      const float4* yrb = (const float4*)(ys + (v + 1) * 64 + w * 16);
      float4 a0 = yra[0], a1 = yra[1], a2 = yra[2], a3 = yra[3];
      float4 b0 = yrb[0], b1 = yrb[1], b2 = yrb[2], b3 = yrb[3];
      float2 xa = *(const float2*)(xs + v * 128 + j);
      float2 xb = *(const float2*)(xs + (v + 1) * 128 + j);
      float yas[16] = {a0.x, a0.y, a0.z, a0.w, a1.x, a1.y, a1.z, a1.w,
                       a2.x, a2.y, a2.z, a2.w, a3.x, a3.y, a3.z, a3.w};
      float ybs[16] = {b0.x, b0.y, b0.z, b0.w, b1.x, b1.y, b1.z, b1.w,
                       b2.x, b2.y, b2.z, b2.w, b3.x, b3.y, b3.z, b3.w};
#pragma unroll
      for (int i = 0; i < 16; i++) {
        acc[i].x += yas[i] * xa.x;
        acc[i].y += yas[i] * xa.y;
      }
#pragma unroll
      for (int i = 0; i < 16; i++) {
        acc[i].x += ybs[i] * xb.x;
        acc[i].y += ybs[i] * xb.y;
      }
    }
    if (v < cc) {
      const float4* yra = (const float4*)(ys + v * 64 + w * 16);
      float4 a0 = yra[0], a1 = yra[1], a2 = yra[2], a3 = yra[3];
      float2 xa = *(const float2*)(xs + v * 128 + j);
      float yas[16] = {a0.x, a0.y, a0.z, a0.w, a1.x, a1.y, a1.z, a1.w,
                       a2.x, a2.y, a2.z, a2.w, a3.x, a3.y, a3.z, a3.w};
#pragma unroll
      for (int i = 0; i < 16; i++) {
        acc[i].x += yas[i] * xa.x;
        acc[i].y += yas[i] * xa.y;
      }
    }
  }

  float* dst = part + (size_t)blockIdx.x * (N_GRAPHS * WIDTH);
#pragma unroll
  for (int i = 0; i < 16; i++)
    *(float2*)(dst + (w * 16 + i) * WIDTH + j) = acc[i];
}

// ---------------- partials reduction, stage 1: 768 rows -> 12 rows ----------------
// grid: 12 row-groups x 32 col-chunks = 384 blocks; coalesced reads, 4 chains.
#define RC_ROWS 64
#define RC_RG (CT_BLOCKS / RC_ROWS)   // 12

__global__ __launch_bounds__(256) void k_reduce1(
    const float* __restrict__ part, float* __restrict__ part2) {
  int bid = blockIdx.x, t = threadIdx.x;
  int rg = bid >> 5, colc = bid & 31;
  int idx = colc * 256 + t;
  const float* src = part + (size_t)rg * RC_ROWS * (N_GRAPHS * WIDTH) + idx;
  float a0 = 0.f, a1 = 0.f, a2 = 0.f, a3 = 0.f;
  for (int r = 0; r < RC_ROWS; r += 4) {
    a0 += src[(size_t)(r + 0) * (N_GRAPHS * WIDTH)];
    a1 += src[(size_t)(r + 1) * (N_GRAPHS * WIDTH)];
    a2 += src[(size_t)(r + 2) * (N_GRAPHS * WIDTH)];
    a3 += src[(size_t)(r + 3) * (N_GRAPHS * WIDTH)];
  }
  part2[rg * (N_GRAPHS * WIDTH) + idx] = (a0 + a1) + (a2 + a3);
}

// O = A*B (128x128 f32); block=row, thread=col
__global__ __launch_bounds__(WIDTH) void k_mm128(
    const float* __restrict__ A, const float* __restrict__ B, float* __restrict__ O) {
  __shared__ float Ar[WIDTH];
  int r = blockIdx.x, j = threadIdx.x;
  Ar[j] = A[r * WIDTH + j];
  __syncthreads();
  float a = 0.f;
#pragma unroll 8
  for (int k = 0; k < WIDTH; k++) a += Ar[k] * B[k * WIDTH + j];
  O[r * WIDTH + j] = a;
}

// c0 = b0^T * T1 ; c1 = b1^T * W2
__global__ __launch_bounds__(WIDTH) void k_c01(
    const float* __restrict__ b0, const float* __restrict__ T1,
    const float* __restrict__ b1, const float* __restrict__ W2,
    float* __restrict__ c0, float* __restrict__ c1) {
  __shared__ float s0[WIDTH], s1v[WIDTH];
  int j = threadIdx.x;
  s0[j] = b0[j]; s1v[j] = b1[j];
  __syncthreads();
  float a0 = 0.f, a1 = 0.f;
#pragma unroll 8
  for (int k = 0; k < WIDTH; k++) {
    a0 += s0[k] * T1[k * WIDTH + j];
    a1 += s1v[k] * W2[k * WIDTH + j];
  }
  c0[j] = a0; c1[j] = a1;
}

// out[g][j]: final 12-row C-sum fused in.
__global__ __launch_bounds__(WIDTH) void k_out(
    const float* __restrict__ part2, const float* __restrict__ Wp,
    const float* __restrict__ c0, const float* __restrict__ c1,
    const float* __restrict__ ps, const float* __restrict__ pas,
    const int* __restrict__ cntg, const float* __restrict__ b2,
    float* __restrict__ out) {
  __shared__ float Cr[WIDTH];
  int g = blockIdx.x, j = threadIdx.x;
  float cv = 0.f;
#pragma unroll
  for (int rg = 0; rg < RC_RG; rg++)
    cv += part2[rg * (N_GRAPHS * WIDTH) + g * WIDTH + j];
  Cr[j] = cv;
  __syncthreads();
  float a = pas[g] * c0[j] + ps[g] * c1[j] + ((cntg[g] > 0) ? b2[j] : 0.f);
#pragma unroll 8
  for (int k = 0; k < WIDTH; k++) a += Cr[k] * Wp[k * WIDTH + j];
  out[g * WIDTH + j] = a;
}

// ---------------- launch ----------------

extern "C" void kernel_launch(void* const* d_in, const int* in_sizes, int n_in,
                              void* d_out, int out_size, void* d_ws, size_t ws_size,
                              hipStream_t stream) {
  const float* x   = (const float*)d_in[0];
  const int* row   = (const int*)d_in[1];         // edge_index[0]
  const int* col   = row + N_EDGES;               // edge_index[1]
  const float* ew  = (const float*)d_in[2];
  const int* batch = (const int*)d_in[3];
  const float* Ws  = (const float*)d_in[4];
  const float* bs  = (const float*)d_in[5];
  float* out = (float*)d_out;

  char* w = (char*)d_ws;
  float* dinv    = (float*)(w + 0);
  float* s_      = (float*)(w + 400128);
  float* as_     = (float*)(w + 800256);
  int*   counts  = (int*)(w + 1200384);
  int*   counts2 = (int*)(w + 1600512);
  int*   offs    = (int*)(w + 2000640);
  int*   offs2   = (int*)(w + 2400768);
  int*   cursor  = (int*)(w + 2800896);
  int*   cursor2 = (int*)(w + 3201024);
  int*   bsum    = (int*)(w + 3601152);
  int*   bsum2   = (int*)(w + 3601664);
  int*   cntg    = (int*)(w + 3602176);
  float* invc    = (float*)(w + 3602432);
  float* ps      = (float*)(w + 3602688);
  float* pas     = (float*)(w + 3602944);
  float* T1      = (float*)(w + 3603200);
  float* Wp      = (float*)(w + 3668736);
  float* c0      = (float*)(w + 3734272);
  float* c1      = (float*)(w + 3734784);
  int*   csr_r   = (int*)(w + 3768064);
  float* csr_n   = (float*)(w + 6328064);
  int*   csr2_c  = (int*)(w + 8888064);
  float* csr2_n  = (float*)(w + 11448064);
  float* part    = (float*)(w + 14008064);   // 768*8192*4 = 25.2 MB
  float* part2   = (float*)(w + 39173888);   // 12*8192*4
  float* yA      = (float*)(w + 47562496);   // N*64 f32
  float* yB      = (float*)(w + 73162496);   // N*64 f32

  int nb_n = (N_NODES + 255) / 256;
  int nb_e = (N_EDGES + 255) / 256;

  k_init <<<nb_n, 256, 0, stream>>>(counts, counts2);
  k_count<<<nb_e, 256, 0, stream>>>(row, col, counts, counts2);
  // col-CSR scan
  k_scan1<<<NBLK, 256, 0, stream>>>(counts, bsum);
  k_scan2<<<1, 64, 0, stream>>>(bsum);
  k_scan3<<<NBLK, 256, 0, stream>>>(counts, bsum, offs, cursor);
  // row-CSR scan
  k_scan1<<<NBLK, 256, 0, stream>>>(counts2, bsum2);
  k_scan2<<<1, 64, 0, stream>>>(bsum2);
  k_scan3<<<NBLK, 256, 0, stream>>>(counts2, bsum2, offs2, cursor2);

  k_fill <<<nb_e, 256, 0, stream>>>(row, col, ew, cursor, csr_r, csr_n);
  k_dinv <<<nb_n, 256, 0, stream>>>(offs, csr_n, dinv);
  k_norm <<<nb_n, 256, 0, stream>>>(offs, csr_r, dinv, csr_n, s_);
  k_fill2<<<nb_e, 256, 0, stream>>>(row, col, ew, dinv, cursor2, csr2_c, csr2_n);

  k_cntg <<<1, 64, 0, stream>>>(batch, cntg, invc);
  k_pinit<<<2048, 256, 0, stream>>>(batch, invc, yA);

  k_as   <<<nb_n, 256, 0, stream>>>(offs, csr_r, csr_n, dinv, s_, as_);
  k_psum <<<N_GRAPHS, 256, 0, stream>>>(batch, invc, s_, as_, ps, pas);

  int nb_y = (N_NODES + AGG_NPB - 1) / AGG_NPB;
  k_yagg<<<nb_y, 256, 0, stream>>>(yA, offs2, csr2_c, csr2_n, dinv, yB);  // y1
  k_yagg<<<nb_y, 256, 0, stream>>>(yB, offs2, csr2_c, csr2_n, dinv, yA);  // y2
  k_yagg<<<nb_y, 256, 0, stream>>>(yA, offs2, csr2_c, csr2_n, dinv, yB);  // y3

  k_mm128<<<WIDTH, WIDTH, 0, stream>>>(Ws + 1 * WIDTH * WIDTH, Ws + 2 * WIDTH * WIDTH, T1);
  k_mm128<<<WIDTH, WIDTH, 0, stream>>>(Ws + 0 * WIDTH * WIDTH, T1, Wp);
  k_c01  <<<1, WIDTH, 0, stream>>>(bs, T1, bs + WIDTH, Ws + 2 * WIDTH * WIDTH, c0, c1);

  k_contract<<<CT_BLOCKS, 256, 0, stream>>>(x, yB, part);
  k_reduce1 <<<RC_RG * 32, 256, 0, stream>>>(part, part2);
  k_out     <<<N_GRAPHS, WIDTH, 0, stream>>>(part2, Wp, c0, c1, ps, pas, cntg,
                                             bs + 2 * WIDTH, out);
}